// Round 8
// baseline (383.807 us; speedup 1.0000x reference)
//
#include <hip/hip_runtime.h>

#define H 16
#define D 24
#define DS 384
#define CZ 128
#define S 512
#define EPSV 1e-5f

// ================= Kernel 1: tiled Q/K/V/G projections (r7, passing) =================
__global__ __launch_bounds__(256) void proj_kernel(
    const float* __restrict__ s, const float* __restrict__ q_w, const float* __restrict__ q_b,
    const float* __restrict__ k_w, const float* __restrict__ v_w, const float* __restrict__ g_w,
    float* __restrict__ Q, float* __restrict__ K, float* __restrict__ V, float* __restrict__ G)
{
    const int b = blockIdx.x;
    const int mat = b / 48;          // 0:Q 1:K 2:V 3:G
    const int t = b % 48;
    const int by = t / 6, bx = t % 6;
    const float* w = (mat == 0) ? q_w : (mat == 1) ? k_w : (mat == 2) ? v_w : g_w;

    __shared__ float As[32][68];
    __shared__ float Ws[32][68];

    const int tid = threadIdx.x;
    const int tx = tid & 15, ty = tid >> 4;
    const int r8 = tid >> 3;
    const int c4 = tid & 7;

    float acc[4][4] = {};
    for (int kc = 0; kc < DS; kc += 32) {
        __syncthreads();
#pragma unroll
        for (int pass = 0; pass < 2; ++pass) {
            int r = r8 + pass * 32;
            float4 sv = *(const float4*)(s + (by * 64 + r) * DS + kc + c4 * 4);
            float4 wv = *(const float4*)(w + (bx * 64 + r) * DS + kc + c4 * 4);
            As[c4 * 4 + 0][r] = sv.x; As[c4 * 4 + 1][r] = sv.y;
            As[c4 * 4 + 2][r] = sv.z; As[c4 * 4 + 3][r] = sv.w;
            Ws[c4 * 4 + 0][r] = wv.x; Ws[c4 * 4 + 1][r] = wv.y;
            Ws[c4 * 4 + 2][r] = wv.z; Ws[c4 * 4 + 3][r] = wv.w;
        }
        __syncthreads();
#pragma unroll
        for (int k = 0; k < 32; ++k) {
            float4 a4 = *(const float4*)&As[k][ty * 4];
            float4 b4 = *(const float4*)&Ws[k][tx * 4];
            acc[0][0] += a4.x * b4.x; acc[0][1] += a4.x * b4.y; acc[0][2] += a4.x * b4.z; acc[0][3] += a4.x * b4.w;
            acc[1][0] += a4.y * b4.x; acc[1][1] += a4.y * b4.y; acc[1][2] += a4.y * b4.z; acc[1][3] += a4.y * b4.w;
            acc[2][0] += a4.z * b4.x; acc[2][1] += a4.z * b4.y; acc[2][2] += a4.z * b4.z; acc[2][3] += a4.z * b4.w;
            acc[3][0] += a4.w * b4.x; acc[3][1] += a4.w * b4.y; acc[3][2] += a4.w * b4.z; acc[3][3] += a4.w * b4.w;
        }
    }

    const int r0 = by * 64 + ty * 4;
    const int c0 = bx * 64 + tx * 4;
    float* dst = (mat == 0) ? Q : (mat == 1) ? K : (mat == 2) ? V : G;
#pragma unroll
    for (int ii = 0; ii < 4; ++ii) {
        float4 v;
        v.x = acc[ii][0]; v.y = acc[ii][1]; v.z = acc[ii][2]; v.w = acc[ii][3];
        if (mat == 0) {
            v.x += q_b[c0 + 0]; v.y += q_b[c0 + 1]; v.z += q_b[c0 + 2]; v.w += q_b[c0 + 3];
        } else if (mat == 3) {
            v.x = 1.f / (1.f + __expf(-v.x)); v.y = 1.f / (1.f + __expf(-v.y));
            v.z = 1.f / (1.f + __expf(-v.z)); v.w = 1.f / (1.f + __expf(-v.w));
        }
        *(float4*)(dst + (r0 + ii) * DS + c0) = v;
    }
}

// ================= Kernel 2a: time-tiled staged-z scores =================
// grid 2048: b = q*4 + jt, 128 key rows/block. Thread = (r = tid>>2, hq = tid&3);
// each thread owns rows {r, r+64} x heads {hq*4..hq*4+3}.
// Per 32-ch chunk: z staged coalesced FULL-LINE (8 lines/wave-inst); per 16-ch sub-chunk
// a loaded to regs (areg[4][4]) once, reused for BOTH row tiles -> a-LDS per row halved
// vs r3. zs reads: 16 rows x 4-lane broadcast at stride 36 (r/r+8 2-way = free).
// dza + LN stats complete per-thread (no opart/stats/phase2). Q from global (L2-hot).
// buf aliases dead zs. LDS ~27KB.
__global__ __launch_bounds__(256) void score_kernel(
    const float* __restrict__ z, const float* __restrict__ seq_mask,
    const float* __restrict__ z_ln_w, const float* __restrict__ z_ln_b,
    const float* __restrict__ z_w,
    const float* __restrict__ Q, const float* __restrict__ K,
    float* __restrict__ scores)
{
    const int b = blockIdx.x;
    const int q = b >> 2;
    const int j0 = (b & 3) * 128;
    const int tid = threadIdx.x;
    const int r = tid >> 2;       // local row 0..63 (tiles at +0, +64)
    const int hq = tid & 3;       // head quad

    __shared__ float a_s[H][CZ + 4];   // folded lnw*zw   8.4 KB
    __shared__ float AhBh[2][H];       //                 128 B
    __shared__ float zs[128 * 36];     // z chunk stage   18.4 KB (buf aliases)

    // ---- Phase 0: stage a_s (+Ah/Bh) ----
    {
        const int h = tid >> 4;           // 0..15
        const int c8 = (tid & 15) * 8;    // 8 channels each
        float A = 0.f, Bv = 0.f;
#pragma unroll
        for (int p = 0; p < 2; ++p) {
            float4 wz = *(const float4*)(z_w + h * CZ + c8 + p * 4);
            float4 lw = *(const float4*)(z_ln_w + c8 + p * 4);
            float4 lb = *(const float4*)(z_ln_b + c8 + p * 4);
            float4 a;
            a.x = lw.x * wz.x; a.y = lw.y * wz.y; a.z = lw.z * wz.z; a.w = lw.w * wz.w;
            *(float4*)&a_s[h][c8 + p * 4] = a;
            A += a.x + a.y + a.z + a.w;
            Bv += lb.x * wz.x + lb.y * wz.y + lb.z * wz.z + lb.w * wz.w;
        }
#pragma unroll
        for (int m = 1; m < 16; m <<= 1) {
            A += __shfl_xor(A, m);
            Bv += __shfl_xor(Bv, m);
        }
        if ((tid & 15) == 0) { AhBh[0][h] = A; AhBh[1][h] = Bv; }
    }
    __syncthreads();

    float accz[2][4] = {};
    float s1[2] = {0.f, 0.f}, s2[2] = {0.f, 0.f};
    const float* zq = z + ((long)q * S + j0) * CZ;

    // ---- dza GEMM + LN stats: 4 staged 32-ch chunks, 2 sub-chunks each ----
    for (int cc = 0; cc < 4; ++cc) {
        const int c0 = cc * 32;
        // stage 128 rows x 32 ch, full-line coalesced (8 lanes cover one 128B line)
#pragma unroll
        for (int it = 0; it < 4; ++it) {
            const int idx = it * 256 + tid;
            const int row = idx >> 3, c8 = idx & 7;
            float4 v = *(const float4*)(zq + (long)row * CZ + c0 + c8 * 4);
            *(float4*)&zs[row * 36 + c8 * 4] = v;
        }
        __syncthreads();

#pragma unroll
        for (int sub = 0; sub < 2; ++sub) {
            const int cb = sub * 16;
            float4 areg[4][4];            // 4 heads x 16 ch, reused across both tiles
#pragma unroll
            for (int i = 0; i < 4; ++i)
#pragma unroll
                for (int t = 0; t < 4; ++t)
                    areg[i][t] = *(const float4*)&a_s[hq * 4 + i][c0 + cb + t * 4];

#pragma unroll
            for (int tl = 0; tl < 2; ++tl) {
                const int row = tl * 64 + r;
                float4 zf[4];
#pragma unroll
                for (int t = 0; t < 4; ++t)
                    zf[t] = *(const float4*)&zs[row * 36 + cb + t * 4];
#pragma unroll
                for (int t = 0; t < 4; ++t) {
                    s1[tl] += zf[t].x + zf[t].y + zf[t].z + zf[t].w;
                    s2[tl] += zf[t].x * zf[t].x + zf[t].y * zf[t].y
                            + zf[t].z * zf[t].z + zf[t].w * zf[t].w;
                }
#pragma unroll
                for (int i = 0; i < 4; ++i) {
                    accz[tl][i] += zf[0].x * areg[i][0].x + zf[0].y * areg[i][0].y
                                 + zf[0].z * areg[i][0].z + zf[0].w * areg[i][0].w
                                 + zf[1].x * areg[i][1].x + zf[1].y * areg[i][1].y
                                 + zf[1].z * areg[i][1].z + zf[1].w * areg[i][1].w
                                 + zf[2].x * areg[i][2].x + zf[2].y * areg[i][2].y
                                 + zf[2].z * areg[i][2].z + zf[2].w * areg[i][2].w
                                 + zf[3].x * areg[i][3].x + zf[3].y * areg[i][3].y
                                 + zf[3].z * areg[i][3].z + zf[3].w * areg[i][3].w;
                }
            }
        }
        __syncthreads();   // zs reads done before next stage overwrites
    }

    // ---- qk: Q from global (L2-hot, broadcast), K streamed per-row ----
    float qk[2][4];
#pragma unroll
    for (int i = 0; i < 4; ++i) {
        const int h = hq * 4 + i;
        float4 qreg[6];
#pragma unroll
        for (int t = 0; t < 6; ++t)
            qreg[t] = *(const float4*)(Q + q * DS + h * D + t * 4);
#pragma unroll
        for (int tl = 0; tl < 2; ++tl) {
            const float4* kp = (const float4*)(K + (long)(j0 + tl * 64 + r) * DS + h * D);
            float a = 0.f;
#pragma unroll
            for (int t = 0; t < 6; ++t) {
                float4 kv = kp[t];
                a += kv.x * qreg[t].x + kv.y * qreg[t].y + kv.z * qreg[t].z + kv.w * qreg[t].w;
            }
            qk[tl][i] = a;
        }
    }

    // ---- epilogue: LN affine + combine; buf aliases zs (no reads after last barrier) ----
    float* buf = zs;                  // [H][132]
    const float scale = 0.2041241452319315f;  // 1/sqrt(24)
#pragma unroll
    for (int tl = 0; tl < 2; ++tl) {
        const int row = tl * 64 + r;
        const float mu = s1[tl] * (1.f / 128.f);
        const float rs = rsqrtf(s2[tl] * (1.f / 128.f) - mu * mu + EPSV);
        const float mk = seq_mask[j0 + row];
#pragma unroll
        for (int i = 0; i < 4; ++i) {
            const int h = hq * 4 + i;
            const float bias = rs * accz[tl][i] - mu * rs * AhBh[0][h] + AhBh[1][h];
            buf[h * 132 + row] = qk[tl][i] * scale + bias + mk;
        }
    }
    __syncthreads();

    // coalesced store: 16 heads x 32 float4, 2 per thread
#pragma unroll
    for (int it = 0; it < 2; ++it) {
        const int idx = it * 256 + tid;
        const int h = idx >> 5, j4 = idx & 31;
        float4 v = *(const float4*)&buf[h * 132 + j4 * 4];
        *(float4*)(scores + ((q << 4) + h) * S + j0 + j4 * 4) = v;
    }
}

// ================= Kernel 2b: softmax + PV + gate, coalesced V (r7, passing) =================
__global__ __launch_bounds__(256) void spv_kernel(
    const float* __restrict__ scores, const float* __restrict__ V,
    const float* __restrict__ G, float* __restrict__ og)
{
    const int q = blockIdx.x;
    const int tid = threadIdx.x;
    const int wv = tid >> 6;
    const int lane = tid & 63;

    __shared__ float sc[H][S + 4];
    __shared__ float opart[4][DS];
    __shared__ float inv_l[H];

    for (int i = tid; i < H * (S / 4); i += 256) {
        int row = i >> 7, f4 = i & 127;
        float4 v = ((const float4*)(scores + ((q << 4) + row) * S))[f4];
        *(float4*)&sc[row][f4 * 4] = v;
    }
    __syncthreads();

#pragma unroll
    for (int i = 0; i < 4; ++i) {
        int h = wv * 4 + i;
        float m = -1e30f;
        for (int j = lane; j < S; j += 64) m = fmaxf(m, sc[h][j]);
#pragma unroll
        for (int mk = 1; mk < 64; mk <<= 1) m = fmaxf(m, __shfl_xor(m, mk));
        float sum = 0.f;
        for (int j = lane; j < S; j += 64) {
            float p = __expf(sc[h][j] - m);
            sc[h][j] = p;
            sum += p;
        }
#pragma unroll
        for (int mk = 1; mk < 64; mk <<= 1) sum += __shfl_xor(sum, mk);
        if (lane == 0) inv_l[h] = 1.f / sum;
    }
    __syncthreads();

    // ---- PV: wave wv -> j in [wv*128, wv*128+128); lane -> c0 = lane*4 (+ c1 for lane<32)
    {
        const int jb = wv * 128;
        const int c0 = lane * 4;
        const int h0 = c0 / 24;
        const int c1 = 256 + lane * 4;            // only lanes 0..31
        const int h1 = c1 / 24;                   // <=15 for lane<32
        float4 a0 = {0.f, 0.f, 0.f, 0.f};
        float4 a1 = {0.f, 0.f, 0.f, 0.f};
#pragma unroll 4
        for (int jj = 0; jj < 128; ++jj) {
            const int j = jb + jj;
            const float4* vr = (const float4*)(V + (long)j * DS);
            const float p0 = sc[h0][j];
            float4 v0 = vr[lane];
            a0.x += p0 * v0.x; a0.y += p0 * v0.y; a0.z += p0 * v0.z; a0.w += p0 * v0.w;
            if (lane < 32) {
                const float p1 = sc[h1][j];
                float4 v1 = vr[64 + lane];
                a1.x += p1 * v1.x; a1.y += p1 * v1.y; a1.z += p1 * v1.z; a1.w += p1 * v1.w;
            }
        }
        *(float4*)&opart[wv][c0] = a0;
        if (lane < 32) *(float4*)&opart[wv][c1] = a1;
    }
    __syncthreads();
    for (int i = tid; i < DS; i += 256) {
        float o = opart[0][i] + opart[1][i] + opart[2][i] + opart[3][i];
        int h = i / 24;
        og[q * DS + i] = o * inv_l[h] * G[q * DS + i];
    }
}

// ================= Kernel 3: tiled output projection (baseline, passing) =================
__global__ __launch_bounds__(256) void out_kernel(
    const float* __restrict__ og, const float* __restrict__ o_w, float* __restrict__ out)
{
    const int b = blockIdx.x;
    const int by = b / 6, bx = b % 6;

    __shared__ float As[32][68];
    __shared__ float Ws[32][68];

    const int tid = threadIdx.x;
    const int tx = tid & 15, ty = tid >> 4;
    const int r8 = tid >> 3;
    const int c4 = tid & 7;

    float acc[4][4] = {};
    for (int kc = 0; kc < DS; kc += 32) {
        __syncthreads();
#pragma unroll
        for (int pass = 0; pass < 2; ++pass) {
            int r = r8 + pass * 32;
            float4 sv = *(const float4*)(og + (by * 64 + r) * DS + kc + c4 * 4);
            float4 wvv = *(const float4*)(o_w + (bx * 64 + r) * DS + kc + c4 * 4);
            As[c4 * 4 + 0][r] = sv.x; As[c4 * 4 + 1][r] = sv.y;
            As[c4 * 4 + 2][r] = sv.z; As[c4 * 4 + 3][r] = sv.w;
            Ws[c4 * 4 + 0][r] = wvv.x; Ws[c4 * 4 + 1][r] = wvv.y;
            Ws[c4 * 4 + 2][r] = wvv.z; Ws[c4 * 4 + 3][r] = wvv.w;
        }
        __syncthreads();
#pragma unroll
        for (int k = 0; k < 32; ++k) {
            float4 a4 = *(const float4*)&As[k][ty * 4];
            float4 b4 = *(const float4*)&Ws[k][tx * 4];
            acc[0][0] += a4.x * b4.x; acc[0][1] += a4.x * b4.y; acc[0][2] += a4.x * b4.z; acc[0][3] += a4.x * b4.w;
            acc[1][0] += a4.y * b4.x; acc[1][1] += a4.y * b4.y; acc[1][2] += a4.y * b4.z; acc[1][3] += a4.y * b4.w;
            acc[2][0] += a4.z * b4.x; acc[2][1] += a4.z * b4.y; acc[2][2] += a4.z * b4.z; acc[2][3] += a4.z * b4.w;
            acc[3][0] += a4.w * b4.x; acc[3][1] += a4.w * b4.y; acc[3][2] += a4.w * b4.z; acc[3][3] += a4.w * b4.w;
        }
    }

    const int r0 = by * 64 + ty * 4;
    const int c0 = bx * 64 + tx * 4;
#pragma unroll
    for (int ii = 0; ii < 4; ++ii) {
        float4 v;
        v.x = acc[ii][0]; v.y = acc[ii][1]; v.z = acc[ii][2]; v.w = acc[ii][3];
        *(float4*)(out + (r0 + ii) * DS + c0) = v;
    }
}

extern "C" void kernel_launch(void* const* d_in, const int* in_sizes, int n_in,
                              void* d_out, int out_size, void* d_ws, size_t ws_size,
                              hipStream_t stream)
{
    const float* s      = (const float*)d_in[0];
    const float* z      = (const float*)d_in[1];
    const float* mask   = (const float*)d_in[2];
    const float* q_w    = (const float*)d_in[3];
    const float* q_b    = (const float*)d_in[4];
    const float* k_w    = (const float*)d_in[5];
    const float* v_w    = (const float*)d_in[6];
    const float* g_w    = (const float*)d_in[7];
    const float* o_w    = (const float*)d_in[8];
    const float* z_ln_w = (const float*)d_in[9];
    const float* z_ln_b = (const float*)d_in[10];
    const float* z_w    = (const float*)d_in[11];

    float* Q  = (float*)d_ws;
    float* K  = Q + S * DS;
    float* V  = K + S * DS;                 // natural [S][H*D] layout
    float* G  = V + S * DS;
    float* og = G + S * DS;
    float* scores = og + S * DS;            // H*S*S floats = 16.8 MB

    hipLaunchKernelGGL(proj_kernel, dim3(192), dim3(256), 0, stream,
                       s, q_w, q_b, k_w, v_w, g_w, Q, K, V, G);
    hipLaunchKernelGGL(score_kernel, dim3(2048), dim3(256), 0, stream,
                       z, mask, z_ln_w, z_ln_b, z_w, Q, K, scores);
    hipLaunchKernelGGL(spv_kernel, dim3(S), dim3(256), 0, stream,
                       scores, V, G, og);
    hipLaunchKernelGGL(out_kernel, dim3(48), dim3(256), 0, stream,
                       og, o_w, (float*)d_out);
}

// Round 9
// 380.945 us; speedup vs baseline: 1.0075x; 1.0075x over previous
//
#include <hip/hip_runtime.h>

#define H 16
#define D 24
#define DS 384
#define CZ 128
#define S 512
#define EPSV 1e-5f

// ================= Kernel 1: tiled Q/K/V/G projections (r7, passing) =================
__global__ __launch_bounds__(256) void proj_kernel(
    const float* __restrict__ s, const float* __restrict__ q_w, const float* __restrict__ q_b,
    const float* __restrict__ k_w, const float* __restrict__ v_w, const float* __restrict__ g_w,
    float* __restrict__ Q, float* __restrict__ K, float* __restrict__ V, float* __restrict__ G)
{
    const int b = blockIdx.x;
    const int mat = b / 48;          // 0:Q 1:K 2:V 3:G
    const int t = b % 48;
    const int by = t / 6, bx = t % 6;
    const float* w = (mat == 0) ? q_w : (mat == 1) ? k_w : (mat == 2) ? v_w : g_w;

    __shared__ float As[32][68];
    __shared__ float Ws[32][68];

    const int tid = threadIdx.x;
    const int tx = tid & 15, ty = tid >> 4;
    const int r8 = tid >> 3;
    const int c4 = tid & 7;

    float acc[4][4] = {};
    for (int kc = 0; kc < DS; kc += 32) {
        __syncthreads();
#pragma unroll
        for (int pass = 0; pass < 2; ++pass) {
            int r = r8 + pass * 32;
            float4 sv = *(const float4*)(s + (by * 64 + r) * DS + kc + c4 * 4);
            float4 wv = *(const float4*)(w + (bx * 64 + r) * DS + kc + c4 * 4);
            As[c4 * 4 + 0][r] = sv.x; As[c4 * 4 + 1][r] = sv.y;
            As[c4 * 4 + 2][r] = sv.z; As[c4 * 4 + 3][r] = sv.w;
            Ws[c4 * 4 + 0][r] = wv.x; Ws[c4 * 4 + 1][r] = wv.y;
            Ws[c4 * 4 + 2][r] = wv.z; Ws[c4 * 4 + 3][r] = wv.w;
        }
        __syncthreads();
#pragma unroll
        for (int k = 0; k < 32; ++k) {
            float4 a4 = *(const float4*)&As[k][ty * 4];
            float4 b4 = *(const float4*)&Ws[k][tx * 4];
            acc[0][0] += a4.x * b4.x; acc[0][1] += a4.x * b4.y; acc[0][2] += a4.x * b4.z; acc[0][3] += a4.x * b4.w;
            acc[1][0] += a4.y * b4.x; acc[1][1] += a4.y * b4.y; acc[1][2] += a4.y * b4.z; acc[1][3] += a4.y * b4.w;
            acc[2][0] += a4.z * b4.x; acc[2][1] += a4.z * b4.y; acc[2][2] += a4.z * b4.z; acc[2][3] += a4.z * b4.w;
            acc[3][0] += a4.w * b4.x; acc[3][1] += a4.w * b4.y; acc[3][2] += a4.w * b4.z; acc[3][3] += a4.w * b4.w;
        }
    }

    const int r0 = by * 64 + ty * 4;
    const int c0 = bx * 64 + tx * 4;
    float* dst = (mat == 0) ? Q : (mat == 1) ? K : (mat == 2) ? V : G;
#pragma unroll
    for (int ii = 0; ii < 4; ++ii) {
        float4 v;
        v.x = acc[ii][0]; v.y = acc[ii][1]; v.z = acc[ii][2]; v.w = acc[ii][3];
        if (mat == 0) {
            v.x += q_b[c0 + 0]; v.y += q_b[c0 + 1]; v.z += q_b[c0 + 2]; v.w += q_b[c0 + 3];
        } else if (mat == 3) {
            v.x = 1.f / (1.f + __expf(-v.x)); v.y = 1.f / (1.f + __expf(-v.y));
            v.z = 1.f / (1.f + __expf(-v.z)); v.w = 1.f / (1.f + __expf(-v.w));
        }
        *(float4*)(dst + (r0 + ii) * DS + c0) = v;
    }
}

// ================= Kernel 2a: shuffle-reduced scores (r3 grid, no cross-wave LDS) =================
// grid 4096: b = q*8 + jt, 64 rows/block, 4 waves x 16 rows. Lane = (r = lane>>2, c = lane&3):
// lane owns row w*16+r, channel slice [c*32, c*32+32).
// z-load pattern IDENTICAL to r3's proven one (lane-private line, 8 consecutive float4).
// dza + LN stats reduced over the 4 c-lanes via __shfl_xor(1,2) -> opart/stats/qrow/phase2
// deleted, barriers 3->2, LDS 34.3->13.7 KB. a_s padded [H][4][36] so the 4 slice
// addresses hit distinct banks (conflict-free 4-addr broadcast).
__global__ __launch_bounds__(256) void score_kernel(
    const float* __restrict__ z, const float* __restrict__ seq_mask,
    const float* __restrict__ z_ln_w, const float* __restrict__ z_ln_b,
    const float* __restrict__ z_w,
    const float* __restrict__ Q, const float* __restrict__ K,
    float* __restrict__ scores)
{
    const int b = blockIdx.x;
    const int q = b >> 3;
    const int j0 = (b & 7) * 64;
    const int tid = threadIdx.x;
    const int w = tid >> 6;
    const int lane = tid & 63;
    const int r = lane >> 2;       // row within wave tile (0..15)
    const int c = lane & 3;        // 32-ch slice
    const int row = w * 16 + r;    // row within block (0..63)

    __shared__ float a_s[H][4][36];    // folded lnw*zw, slice-padded  9.2 KB
    __shared__ float AhBh[2][H];       //                              128 B
    __shared__ float buf[H][68];       // output transpose             4.3 KB

    // ---- Phase 0: stage a_s (+Ah/Bh) ----
    {
        const int h = tid >> 4;           // 0..15
        const int c8 = (tid & 15) * 8;    // 8 channels each
        float A = 0.f, Bv = 0.f;
#pragma unroll
        for (int p = 0; p < 2; ++p) {
            const int ch = c8 + p * 4;
            float4 wz = *(const float4*)(z_w + h * CZ + ch);
            float4 lw = *(const float4*)(z_ln_w + ch);
            float4 lb = *(const float4*)(z_ln_b + ch);
            float4 a;
            a.x = lw.x * wz.x; a.y = lw.y * wz.y; a.z = lw.z * wz.z; a.w = lw.w * wz.w;
            *(float4*)&a_s[h][ch >> 5][ch & 31] = a;
            A += a.x + a.y + a.z + a.w;
            Bv += lb.x * wz.x + lb.y * wz.y + lb.z * wz.z + lb.w * wz.w;
        }
#pragma unroll
        for (int m = 1; m < 16; m <<= 1) {
            A += __shfl_xor(A, m);
            Bv += __shfl_xor(Bv, m);
        }
        if ((tid & 15) == 0) { AhBh[0][h] = A; AhBh[1][h] = Bv; }
    }
    __syncthreads();

    // ---- Phase 1: z -> regs (lane-private line), dza for all 16 heads + LN stats ----
    const float* zr = z + ((long)q * S + j0 + row) * CZ + c * 32;
    float4 zf[8];
#pragma unroll
    for (int t = 0; t < 8; ++t) zf[t] = *(const float4*)(zr + t * 4);

    float s1 = 0.f, s2 = 0.f;
#pragma unroll
    for (int t = 0; t < 8; ++t) {
        s1 += zf[t].x + zf[t].y + zf[t].z + zf[t].w;
        s2 += zf[t].x * zf[t].x + zf[t].y * zf[t].y + zf[t].z * zf[t].z + zf[t].w * zf[t].w;
    }

    float dza[H];
#pragma unroll
    for (int h = 0; h < H; ++h) {
        float acc = 0.f;
#pragma unroll
        for (int t = 0; t < 8; ++t) {
            float4 a4 = *(const float4*)&a_s[h][c][t * 4];   // 4-addr broadcast, distinct banks
            acc += zf[t].x * a4.x + zf[t].y * a4.y + zf[t].z * a4.z + zf[t].w * a4.w;
        }
        dza[h] = acc;
    }

    // reduce over the 4 c-lanes (lane^1, lane^2)
#pragma unroll
    for (int h = 0; h < H; ++h) {
        dza[h] += __shfl_xor(dza[h], 1);
        dza[h] += __shfl_xor(dza[h], 2);
    }
    s1 += __shfl_xor(s1, 1); s1 += __shfl_xor(s1, 2);
    s2 += __shfl_xor(s2, 1); s2 += __shfl_xor(s2, 2);

    const float mu = s1 * (1.f / 128.f);
    const float rs = rsqrtf(s2 * (1.f / 128.f) - mu * mu + EPSV);
    const float mk = seq_mask[j0 + row];

    // ---- qk: lane handles heads c*4..c*4+3 for its row; Q broadcast, K L2-resident ----
    const float scale = 0.2041241452319315f;  // 1/sqrt(24)
#pragma unroll
    for (int i = 0; i < 4; ++i) {
        const int h = c * 4 + i;
        const float4* q4 = (const float4*)(Q + q * DS + h * D);
        const float4* k4 = (const float4*)(K + (long)(j0 + row) * DS + h * D);
        float qk = 0.f;
#pragma unroll
        for (int t = 0; t < 6; ++t) {
            float4 qv = q4[t];
            float4 kv = k4[t];
            qk += kv.x * qv.x + kv.y * qv.y + kv.z * qv.z + kv.w * qv.w;
        }
        const float bias = rs * dza[h] - mu * rs * AhBh[0][h] + AhBh[1][h];
        buf[h][row] = qk * scale + bias + mk;
    }
    __syncthreads();

    // coalesced store: 16 threads per head, float4 along j
    {
        const int h = tid >> 4, j4 = tid & 15;
        float4 v = *(const float4*)&buf[h][j4 * 4];
        *(float4*)(scores + ((q << 4) + h) * S + j0 + j4 * 4) = v;
    }
}

// ================= Kernel 2b: softmax + PV + gate, coalesced V (r7, passing) =================
__global__ __launch_bounds__(256) void spv_kernel(
    const float* __restrict__ scores, const float* __restrict__ V,
    const float* __restrict__ G, float* __restrict__ og)
{
    const int q = blockIdx.x;
    const int tid = threadIdx.x;
    const int wv = tid >> 6;
    const int lane = tid & 63;

    __shared__ float sc[H][S + 4];
    __shared__ float opart[4][DS];
    __shared__ float inv_l[H];

    for (int i = tid; i < H * (S / 4); i += 256) {
        int row = i >> 7, f4 = i & 127;
        float4 v = ((const float4*)(scores + ((q << 4) + row) * S))[f4];
        *(float4*)&sc[row][f4 * 4] = v;
    }
    __syncthreads();

#pragma unroll
    for (int i = 0; i < 4; ++i) {
        int h = wv * 4 + i;
        float m = -1e30f;
        for (int j = lane; j < S; j += 64) m = fmaxf(m, sc[h][j]);
#pragma unroll
        for (int mk = 1; mk < 64; mk <<= 1) m = fmaxf(m, __shfl_xor(m, mk));
        float sum = 0.f;
        for (int j = lane; j < S; j += 64) {
            float p = __expf(sc[h][j] - m);
            sc[h][j] = p;
            sum += p;
        }
#pragma unroll
        for (int mk = 1; mk < 64; mk <<= 1) sum += __shfl_xor(sum, mk);
        if (lane == 0) inv_l[h] = 1.f / sum;
    }
    __syncthreads();

    // ---- PV: wave wv -> j in [wv*128, wv*128+128); lane -> c0 = lane*4 (+ c1 for lane<32)
    {
        const int jb = wv * 128;
        const int c0 = lane * 4;
        const int h0 = c0 / 24;
        const int c1 = 256 + lane * 4;            // only lanes 0..31
        const int h1 = c1 / 24;                   // <=15 for lane<32
        float4 a0 = {0.f, 0.f, 0.f, 0.f};
        float4 a1 = {0.f, 0.f, 0.f, 0.f};
#pragma unroll 4
        for (int jj = 0; jj < 128; ++jj) {
            const int j = jb + jj;
            const float4* vr = (const float4*)(V + (long)j * DS);
            const float p0 = sc[h0][j];
            float4 v0 = vr[lane];
            a0.x += p0 * v0.x; a0.y += p0 * v0.y; a0.z += p0 * v0.z; a0.w += p0 * v0.w;
            if (lane < 32) {
                const float p1 = sc[h1][j];
                float4 v1 = vr[64 + lane];
                a1.x += p1 * v1.x; a1.y += p1 * v1.y; a1.z += p1 * v1.z; a1.w += p1 * v1.w;
            }
        }
        *(float4*)&opart[wv][c0] = a0;
        if (lane < 32) *(float4*)&opart[wv][c1] = a1;
    }
    __syncthreads();
    for (int i = tid; i < DS; i += 256) {
        float o = opart[0][i] + opart[1][i] + opart[2][i] + opart[3][i];
        int h = i / 24;
        og[q * DS + i] = o * inv_l[h] * G[q * DS + i];
    }
}

// ================= Kernel 3: tiled output projection (baseline, passing) =================
__global__ __launch_bounds__(256) void out_kernel(
    const float* __restrict__ og, const float* __restrict__ o_w, float* __restrict__ out)
{
    const int b = blockIdx.x;
    const int by = b / 6, bx = b % 6;

    __shared__ float As[32][68];
    __shared__ float Ws[32][68];

    const int tid = threadIdx.x;
    const int tx = tid & 15, ty = tid >> 4;
    const int r8 = tid >> 3;
    const int c4 = tid & 7;

    float acc[4][4] = {};
    for (int kc = 0; kc < DS; kc += 32) {
        __syncthreads();
#pragma unroll
        for (int pass = 0; pass < 2; ++pass) {
            int r = r8 + pass * 32;
            float4 sv = *(const float4*)(og + (by * 64 + r) * DS + kc + c4 * 4);
            float4 wvv = *(const float4*)(o_w + (bx * 64 + r) * DS + kc + c4 * 4);
            As[c4 * 4 + 0][r] = sv.x; As[c4 * 4 + 1][r] = sv.y;
            As[c4 * 4 + 2][r] = sv.z; As[c4 * 4 + 3][r] = sv.w;
            Ws[c4 * 4 + 0][r] = wvv.x; Ws[c4 * 4 + 1][r] = wvv.y;
            Ws[c4 * 4 + 2][r] = wvv.z; Ws[c4 * 4 + 3][r] = wvv.w;
        }
        __syncthreads();
#pragma unroll
        for (int k = 0; k < 32; ++k) {
            float4 a4 = *(const float4*)&As[k][ty * 4];
            float4 b4 = *(const float4*)&Ws[k][tx * 4];
            acc[0][0] += a4.x * b4.x; acc[0][1] += a4.x * b4.y; acc[0][2] += a4.x * b4.z; acc[0][3] += a4.x * b4.w;
            acc[1][0] += a4.y * b4.x; acc[1][1] += a4.y * b4.y; acc[1][2] += a4.y * b4.z; acc[1][3] += a4.y * b4.w;
            acc[2][0] += a4.z * b4.x; acc[2][1] += a4.z * b4.y; acc[2][2] += a4.z * b4.z; acc[2][3] += a4.z * b4.w;
            acc[3][0] += a4.w * b4.x; acc[3][1] += a4.w * b4.y; acc[3][2] += a4.w * b4.z; acc[3][3] += a4.w * b4.w;
        }
    }

    const int r0 = by * 64 + ty * 4;
    const int c0 = bx * 64 + tx * 4;
#pragma unroll
    for (int ii = 0; ii < 4; ++ii) {
        float4 v;
        v.x = acc[ii][0]; v.y = acc[ii][1]; v.z = acc[ii][2]; v.w = acc[ii][3];
        *(float4*)(out + (r0 + ii) * DS + c0) = v;
    }
}

extern "C" void kernel_launch(void* const* d_in, const int* in_sizes, int n_in,
                              void* d_out, int out_size, void* d_ws, size_t ws_size,
                              hipStream_t stream)
{
    const float* s      = (const float*)d_in[0];
    const float* z      = (const float*)d_in[1];
    const float* mask   = (const float*)d_in[2];
    const float* q_w    = (const float*)d_in[3];
    const float* q_b    = (const float*)d_in[4];
    const float* k_w    = (const float*)d_in[5];
    const float* v_w    = (const float*)d_in[6];
    const float* g_w    = (const float*)d_in[7];
    const float* o_w    = (const float*)d_in[8];
    const float* z_ln_w = (const float*)d_in[9];
    const float* z_ln_b = (const float*)d_in[10];
    const float* z_w    = (const float*)d_in[11];

    float* Q  = (float*)d_ws;
    float* K  = Q + S * DS;
    float* V  = K + S * DS;                 // natural [S][H*D] layout
    float* G  = V + S * DS;
    float* og = G + S * DS;
    float* scores = og + S * DS;            // H*S*S floats = 16.8 MB

    hipLaunchKernelGGL(proj_kernel, dim3(192), dim3(256), 0, stream,
                       s, q_w, q_b, k_w, v_w, g_w, Q, K, V, G);
    hipLaunchKernelGGL(score_kernel, dim3(4096), dim3(256), 0, stream,
                       z, mask, z_ln_w, z_ln_b, z_w, Q, K, scores);
    hipLaunchKernelGGL(spv_kernel, dim3(S), dim3(256), 0, stream,
                       scores, V, G, og);
    hipLaunchKernelGGL(out_kernel, dim3(48), dim3(256), 0, stream,
                       og, o_w, (float*)d_out);
}

// Round 10
// 341.016 us; speedup vs baseline: 1.1255x; 1.1171x over previous
//
#include <hip/hip_runtime.h>

#define H 16
#define D 24
#define DS 384
#define CZ 128
#define S 512
#define EPSV 1e-5f

// ================= Kernel 1: tiled Q/K/V/G projections (r7, passing) =================
__global__ __launch_bounds__(256) void proj_kernel(
    const float* __restrict__ s, const float* __restrict__ q_w, const float* __restrict__ q_b,
    const float* __restrict__ k_w, const float* __restrict__ v_w, const float* __restrict__ g_w,
    float* __restrict__ Q, float* __restrict__ K, float* __restrict__ V, float* __restrict__ G)
{
    const int b = blockIdx.x;
    const int mat = b / 48;          // 0:Q 1:K 2:V 3:G
    const int t = b % 48;
    const int by = t / 6, bx = t % 6;
    const float* w = (mat == 0) ? q_w : (mat == 1) ? k_w : (mat == 2) ? v_w : g_w;

    __shared__ float As[32][68];
    __shared__ float Ws[32][68];

    const int tid = threadIdx.x;
    const int tx = tid & 15, ty = tid >> 4;
    const int r8 = tid >> 3;
    const int c4 = tid & 7;

    float acc[4][4] = {};
    for (int kc = 0; kc < DS; kc += 32) {
        __syncthreads();
#pragma unroll
        for (int pass = 0; pass < 2; ++pass) {
            int r = r8 + pass * 32;
            float4 sv = *(const float4*)(s + (by * 64 + r) * DS + kc + c4 * 4);
            float4 wv = *(const float4*)(w + (bx * 64 + r) * DS + kc + c4 * 4);
            As[c4 * 4 + 0][r] = sv.x; As[c4 * 4 + 1][r] = sv.y;
            As[c4 * 4 + 2][r] = sv.z; As[c4 * 4 + 3][r] = sv.w;
            Ws[c4 * 4 + 0][r] = wv.x; Ws[c4 * 4 + 1][r] = wv.y;
            Ws[c4 * 4 + 2][r] = wv.z; Ws[c4 * 4 + 3][r] = wv.w;
        }
        __syncthreads();
#pragma unroll
        for (int k = 0; k < 32; ++k) {
            float4 a4 = *(const float4*)&As[k][ty * 4];
            float4 b4 = *(const float4*)&Ws[k][tx * 4];
            acc[0][0] += a4.x * b4.x; acc[0][1] += a4.x * b4.y; acc[0][2] += a4.x * b4.z; acc[0][3] += a4.x * b4.w;
            acc[1][0] += a4.y * b4.x; acc[1][1] += a4.y * b4.y; acc[1][2] += a4.y * b4.z; acc[1][3] += a4.y * b4.w;
            acc[2][0] += a4.z * b4.x; acc[2][1] += a4.z * b4.y; acc[2][2] += a4.z * b4.z; acc[2][3] += a4.z * b4.w;
            acc[3][0] += a4.w * b4.x; acc[3][1] += a4.w * b4.y; acc[3][2] += a4.w * b4.z; acc[3][3] += a4.w * b4.w;
        }
    }

    const int r0 = by * 64 + ty * 4;
    const int c0 = bx * 64 + tx * 4;
    float* dst = (mat == 0) ? Q : (mat == 1) ? K : (mat == 2) ? V : G;
#pragma unroll
    for (int ii = 0; ii < 4; ++ii) {
        float4 v;
        v.x = acc[ii][0]; v.y = acc[ii][1]; v.z = acc[ii][2]; v.w = acc[ii][3];
        if (mat == 0) {
            v.x += q_b[c0 + 0]; v.y += q_b[c0 + 1]; v.z += q_b[c0 + 2]; v.w += q_b[c0 + 3];
        } else if (mat == 3) {
            v.x = 1.f / (1.f + __expf(-v.x)); v.y = 1.f / (1.f + __expf(-v.y));
            v.z = 1.f / (1.f + __expf(-v.z)); v.w = 1.f / (1.f + __expf(-v.w));
        }
        *(float4*)(dst + (r0 + ii) * DS + c0) = v;
    }
}

// ================= Kernel 2a: register-z + broadcast-a LN/bias/QK scores =================
// r3 structure (97us measured) with ONE fix: qrow padded to [H][28] so phase-2 head
// addresses (diff 112 floats = 16 mod 32 banks) are 2-way instead of 4-way conflicted.
// 2-way is free [m136]. Values/order identical -> numerics unchanged.
__global__ __launch_bounds__(256) void score_kernel(
    const float* __restrict__ z, const float* __restrict__ seq_mask,
    const float* __restrict__ z_ln_w, const float* __restrict__ z_ln_b,
    const float* __restrict__ z_w,
    const float* __restrict__ Q, const float* __restrict__ K,
    float* __restrict__ scores)
{
    const int b = blockIdx.x;
    const int q = b >> 3;
    const int j0 = (b & 7) * 64;
    const int tid = threadIdx.x;
    const int w = tid >> 6;        // wave id -> channel slice
    const int lane = tid & 63;     // key row within tile

    __shared__ float a_s[H][CZ + 4];      // folded lnw*zw        8.4 KB
    __shared__ float AhBh[2][H];          //                      128 B
    __shared__ float qrow[H][28];         // Q row, head-padded   1.75 KB
    __shared__ float stats[4][2][68];     // [wave][sum/sq][row]  2.2 KB
    __shared__ float opart[4][H][68];     // [wave][head][row]    17.4 KB
    __shared__ float buf[H][68];          // output transpose     4.3 KB

    // ---- Phase 0: stage a_s (+Ah/Bh) and qrow ----
    {
        const int h = tid >> 4;           // 0..15
        const int c8 = (tid & 15) * 8;    // 8 channels each
        float A = 0.f, Bv = 0.f;
#pragma unroll
        for (int p = 0; p < 2; ++p) {
            float4 wz = *(const float4*)(z_w + h * CZ + c8 + p * 4);
            float4 lw = *(const float4*)(z_ln_w + c8 + p * 4);
            float4 lb = *(const float4*)(z_ln_b + c8 + p * 4);
            float4 a;
            a.x = lw.x * wz.x; a.y = lw.y * wz.y; a.z = lw.z * wz.z; a.w = lw.w * wz.w;
            *(float4*)&a_s[h][c8 + p * 4] = a;
            A += a.x + a.y + a.z + a.w;
            Bv += lb.x * wz.x + lb.y * wz.y + lb.z * wz.z + lb.w * wz.w;
        }
#pragma unroll
        for (int m = 1; m < 16; m <<= 1) {
            A += __shfl_xor(A, m);
            Bv += __shfl_xor(Bv, m);
        }
        if ((tid & 15) == 0) { AhBh[0][h] = A; AhBh[1][h] = Bv; }
    }
    for (int i = tid; i < DS; i += 256) qrow[i / 24][i % 24] = Q[q * DS + i];
    __syncthreads();

    // ---- Phase 1: per-wave partial GEMM over its 32-channel slice ----
    {
        const int c0 = w * 32;
        const float* zr = z + ((long)q * S + j0 + lane) * CZ + c0;
        float4 zf[8];
#pragma unroll
        for (int t = 0; t < 8; ++t) zf[t] = *(const float4*)(zr + t * 4);

        float s1 = 0.f, s2 = 0.f;
#pragma unroll
        for (int t = 0; t < 8; ++t) {
            s1 += zf[t].x + zf[t].y + zf[t].z + zf[t].w;
            s2 += zf[t].x * zf[t].x + zf[t].y * zf[t].y + zf[t].z * zf[t].z + zf[t].w * zf[t].w;
        }
        stats[w][0][lane] = s1;
        stats[w][1][lane] = s2;

#pragma unroll
        for (int h = 0; h < H; ++h) {
            float acc = 0.f;
#pragma unroll
            for (int t = 0; t < 8; ++t) {
                float4 a4 = *(const float4*)&a_s[h][c0 + t * 4];   // wave-uniform: broadcast
                acc += zf[t].x * a4.x + zf[t].y * a4.y + zf[t].z * a4.z + zf[t].w * a4.w;
            }
            opart[w][h][lane] = acc;
        }
    }
    __syncthreads();

    // ---- Phase 2: combine partials, LN affine + QK, write via transpose buffer ----
    {
        const int r = tid >> 2;           // key row 0..63
        const int hq = tid & 3;           // head quad
        float s1 = stats[0][0][r] + stats[1][0][r] + stats[2][0][r] + stats[3][0][r];
        float s2 = stats[0][1][r] + stats[1][1][r] + stats[2][1][r] + stats[3][1][r];
        const float mu = s1 * (1.f / 128.f);
        const float rs = rsqrtf(s2 * (1.f / 128.f) - mu * mu + EPSV);
        const float mk = seq_mask[j0 + r];
        const float scale = 0.2041241452319315f;  // 1/sqrt(24)
        const float* krow = K + (long)(j0 + r) * DS;

#pragma unroll
        for (int i = 0; i < 4; ++i) {
            const int h = hq * 4 + i;
            float dza = opart[0][h][r] + opart[1][h][r] + opart[2][h][r] + opart[3][h][r];
            const float4* k4 = (const float4*)(krow + h * D);
            const float4* q4 = (const float4*)&qrow[h][0];
            float qk = 0.f;
#pragma unroll
            for (int t = 0; t < 6; ++t) {
                float4 kv = k4[t];
                float4 qv = q4[t];
                qk += kv.x * qv.x + kv.y * qv.y + kv.z * qv.z + kv.w * qv.w;
            }
            const float bias = rs * dza - mu * rs * AhBh[0][h] + AhBh[1][h];
            buf[h][r] = qk * scale + bias + mk;
        }
    }
    __syncthreads();

    // coalesced store: 16 threads per head, float4 along j
    {
        const int h = tid >> 4, j4 = tid & 15;
        float4 v = *(const float4*)&buf[h][j4 * 4];
        *(float4*)(scores + ((q << 4) + h) * S + j0 + j4 * 4) = v;
    }
}

// ================= Kernel 2b: softmax + PV + gate, coalesced V (r7, passing) =================
__global__ __launch_bounds__(256) void spv_kernel(
    const float* __restrict__ scores, const float* __restrict__ V,
    const float* __restrict__ G, float* __restrict__ og)
{
    const int q = blockIdx.x;
    const int tid = threadIdx.x;
    const int wv = tid >> 6;
    const int lane = tid & 63;

    __shared__ float sc[H][S + 4];
    __shared__ float opart[4][DS];
    __shared__ float inv_l[H];

    for (int i = tid; i < H * (S / 4); i += 256) {
        int row = i >> 7, f4 = i & 127;
        float4 v = ((const float4*)(scores + ((q << 4) + row) * S))[f4];
        *(float4*)&sc[row][f4 * 4] = v;
    }
    __syncthreads();

#pragma unroll
    for (int i = 0; i < 4; ++i) {
        int h = wv * 4 + i;
        float m = -1e30f;
        for (int j = lane; j < S; j += 64) m = fmaxf(m, sc[h][j]);
#pragma unroll
        for (int mk = 1; mk < 64; mk <<= 1) m = fmaxf(m, __shfl_xor(m, mk));
        float sum = 0.f;
        for (int j = lane; j < S; j += 64) {
            float p = __expf(sc[h][j] - m);
            sc[h][j] = p;
            sum += p;
        }
#pragma unroll
        for (int mk = 1; mk < 64; mk <<= 1) sum += __shfl_xor(sum, mk);
        if (lane == 0) inv_l[h] = 1.f / sum;
    }
    __syncthreads();

    // ---- PV: wave wv -> j in [wv*128, wv*128+128); lane -> c0 = lane*4 (+ c1 for lane<32)
    {
        const int jb = wv * 128;
        const int c0 = lane * 4;
        const int h0 = c0 / 24;
        const int c1 = 256 + lane * 4;            // only lanes 0..31
        const int h1 = c1 / 24;                   // <=15 for lane<32
        float4 a0 = {0.f, 0.f, 0.f, 0.f};
        float4 a1 = {0.f, 0.f, 0.f, 0.f};
#pragma unroll 4
        for (int jj = 0; jj < 128; ++jj) {
            const int j = jb + jj;
            const float4* vr = (const float4*)(V + (long)j * DS);
            const float p0 = sc[h0][j];
            float4 v0 = vr[lane];
            a0.x += p0 * v0.x; a0.y += p0 * v0.y; a0.z += p0 * v0.z; a0.w += p0 * v0.w;
            if (lane < 32) {
                const float p1 = sc[h1][j];
                float4 v1 = vr[64 + lane];
                a1.x += p1 * v1.x; a1.y += p1 * v1.y; a1.z += p1 * v1.z; a1.w += p1 * v1.w;
            }
        }
        *(float4*)&opart[wv][c0] = a0;
        if (lane < 32) *(float4*)&opart[wv][c1] = a1;
    }
    __syncthreads();
    for (int i = tid; i < DS; i += 256) {
        float o = opart[0][i] + opart[1][i] + opart[2][i] + opart[3][i];
        int h = i / 24;
        og[q * DS + i] = o * inv_l[h] * G[q * DS + i];
    }
}

// ================= Kernel 3: tiled output projection (baseline, passing) =================
__global__ __launch_bounds__(256) void out_kernel(
    const float* __restrict__ og, const float* __restrict__ o_w, float* __restrict__ out)
{
    const int b = blockIdx.x;
    const int by = b / 6, bx = b % 6;

    __shared__ float As[32][68];
    __shared__ float Ws[32][68];

    const int tid = threadIdx.x;
    const int tx = tid & 15, ty = tid >> 4;
    const int r8 = tid >> 3;
    const int c4 = tid & 7;

    float acc[4][4] = {};
    for (int kc = 0; kc < DS; kc += 32) {
        __syncthreads();
#pragma unroll
        for (int pass = 0; pass < 2; ++pass) {
            int r = r8 + pass * 32;
            float4 sv = *(const float4*)(og + (by * 64 + r) * DS + kc + c4 * 4);
            float4 wvv = *(const float4*)(o_w + (bx * 64 + r) * DS + kc + c4 * 4);
            As[c4 * 4 + 0][r] = sv.x; As[c4 * 4 + 1][r] = sv.y;
            As[c4 * 4 + 2][r] = sv.z; As[c4 * 4 + 3][r] = sv.w;
            Ws[c4 * 4 + 0][r] = wvv.x; Ws[c4 * 4 + 1][r] = wvv.y;
            Ws[c4 * 4 + 2][r] = wvv.z; Ws[c4 * 4 + 3][r] = wvv.w;
        }
        __syncthreads();
#pragma unroll
        for (int k = 0; k < 32; ++k) {
            float4 a4 = *(const float4*)&As[k][ty * 4];
            float4 b4 = *(const float4*)&Ws[k][tx * 4];
            acc[0][0] += a4.x * b4.x; acc[0][1] += a4.x * b4.y; acc[0][2] += a4.x * b4.z; acc[0][3] += a4.x * b4.w;
            acc[1][0] += a4.y * b4.x; acc[1][1] += a4.y * b4.y; acc[1][2] += a4.y * b4.z; acc[1][3] += a4.y * b4.w;
            acc[2][0] += a4.z * b4.x; acc[2][1] += a4.z * b4.y; acc[2][2] += a4.z * b4.z; acc[2][3] += a4.z * b4.w;
            acc[3][0] += a4.w * b4.x; acc[3][1] += a4.w * b4.y; acc[3][2] += a4.w * b4.z; acc[3][3] += a4.w * b4.w;
        }
    }

    const int r0 = by * 64 + ty * 4;
    const int c0 = bx * 64 + tx * 4;
#pragma unroll
    for (int ii = 0; ii < 4; ++ii) {
        float4 v;
        v.x = acc[ii][0]; v.y = acc[ii][1]; v.z = acc[ii][2]; v.w = acc[ii][3];
        *(float4*)(out + (r0 + ii) * DS + c0) = v;
    }
}

extern "C" void kernel_launch(void* const* d_in, const int* in_sizes, int n_in,
                              void* d_out, int out_size, void* d_ws, size_t ws_size,
                              hipStream_t stream)
{
    const float* s      = (const float*)d_in[0];
    const float* z      = (const float*)d_in[1];
    const float* mask   = (const float*)d_in[2];
    const float* q_w    = (const float*)d_in[3];
    const float* q_b    = (const float*)d_in[4];
    const float* k_w    = (const float*)d_in[5];
    const float* v_w    = (const float*)d_in[6];
    const float* g_w    = (const float*)d_in[7];
    const float* o_w    = (const float*)d_in[8];
    const float* z_ln_w = (const float*)d_in[9];
    const float* z_ln_b = (const float*)d_in[10];
    const float* z_w    = (const float*)d_in[11];

    float* Q  = (float*)d_ws;
    float* K  = Q + S * DS;
    float* V  = K + S * DS;                 // natural [S][H*D] layout
    float* G  = V + S * DS;
    float* og = G + S * DS;
    float* scores = og + S * DS;            // H*S*S floats = 16.8 MB

    hipLaunchKernelGGL(proj_kernel, dim3(192), dim3(256), 0, stream,
                       s, q_w, q_b, k_w, v_w, g_w, Q, K, V, G);
    hipLaunchKernelGGL(score_kernel, dim3(4096), dim3(256), 0, stream,
                       z, mask, z_ln_w, z_ln_b, z_w, Q, K, scores);
    hipLaunchKernelGGL(spv_kernel, dim3(S), dim3(256), 0, stream,
                       scores, V, G, og);
    hipLaunchKernelGGL(out_kernel, dim3(48), dim3(256), 0, stream,
                       og, o_w, (float*)d_out);
}

// Round 11
// 337.543 us; speedup vs baseline: 1.1371x; 1.0103x over previous
//
#include <hip/hip_runtime.h>

#define H 16
#define D 24
#define DS 384
#define CZ 128
#define S 512
#define EPSV 1e-5f

// ================= Kernel 1: tiled Q/K/V/G projections =================
// V stored in NATURAL [S][H*D] layout (same as K) -> all stores coalesced float4.
__global__ __launch_bounds__(256) void proj_kernel(
    const float* __restrict__ s, const float* __restrict__ q_w, const float* __restrict__ q_b,
    const float* __restrict__ k_w, const float* __restrict__ v_w, const float* __restrict__ g_w,
    float* __restrict__ Q, float* __restrict__ K, float* __restrict__ V, float* __restrict__ G)
{
    const int b = blockIdx.x;
    const int mat = b / 48;          // 0:Q 1:K 2:V 3:G
    const int t = b % 48;
    const int by = t / 6, bx = t % 6;
    const float* w = (mat == 0) ? q_w : (mat == 1) ? k_w : (mat == 2) ? v_w : g_w;

    __shared__ float As[32][68];
    __shared__ float Ws[32][68];

    const int tid = threadIdx.x;
    const int tx = tid & 15, ty = tid >> 4;
    const int r8 = tid >> 3;
    const int c4 = tid & 7;

    float acc[4][4] = {};
    for (int kc = 0; kc < DS; kc += 32) {
        __syncthreads();
#pragma unroll
        for (int pass = 0; pass < 2; ++pass) {
            int r = r8 + pass * 32;
            float4 sv = *(const float4*)(s + (by * 64 + r) * DS + kc + c4 * 4);
            float4 wv = *(const float4*)(w + (bx * 64 + r) * DS + kc + c4 * 4);
            As[c4 * 4 + 0][r] = sv.x; As[c4 * 4 + 1][r] = sv.y;
            As[c4 * 4 + 2][r] = sv.z; As[c4 * 4 + 3][r] = sv.w;
            Ws[c4 * 4 + 0][r] = wv.x; Ws[c4 * 4 + 1][r] = wv.y;
            Ws[c4 * 4 + 2][r] = wv.z; Ws[c4 * 4 + 3][r] = wv.w;
        }
        __syncthreads();
#pragma unroll
        for (int k = 0; k < 32; ++k) {
            float4 a4 = *(const float4*)&As[k][ty * 4];
            float4 b4 = *(const float4*)&Ws[k][tx * 4];
            acc[0][0] += a4.x * b4.x; acc[0][1] += a4.x * b4.y; acc[0][2] += a4.x * b4.z; acc[0][3] += a4.x * b4.w;
            acc[1][0] += a4.y * b4.x; acc[1][1] += a4.y * b4.y; acc[1][2] += a4.y * b4.z; acc[1][3] += a4.y * b4.w;
            acc[2][0] += a4.z * b4.x; acc[2][1] += a4.z * b4.y; acc[2][2] += a4.z * b4.z; acc[2][3] += a4.z * b4.w;
            acc[3][0] += a4.w * b4.x; acc[3][1] += a4.w * b4.y; acc[3][2] += a4.w * b4.z; acc[3][3] += a4.w * b4.w;
        }
    }

    const int r0 = by * 64 + ty * 4;
    const int c0 = bx * 64 + tx * 4;
    float* dst = (mat == 0) ? Q : (mat == 1) ? K : (mat == 2) ? V : G;
#pragma unroll
    for (int ii = 0; ii < 4; ++ii) {
        float4 v;
        v.x = acc[ii][0]; v.y = acc[ii][1]; v.z = acc[ii][2]; v.w = acc[ii][3];
        if (mat == 0) {
            v.x += q_b[c0 + 0]; v.y += q_b[c0 + 1]; v.z += q_b[c0 + 2]; v.w += q_b[c0 + 3];
        } else if (mat == 3) {
            v.x = 1.f / (1.f + __expf(-v.x)); v.y = 1.f / (1.f + __expf(-v.y));
            v.z = 1.f / (1.f + __expf(-v.z)); v.w = 1.f / (1.f + __expf(-v.w));
        }
        *(float4*)(dst + (r0 + ii) * DS + c0) = v;
    }
}

// ================= Kernel 2a: register-z + broadcast-a LN/bias/QK scores (r3, 97us) =================
__global__ __launch_bounds__(256) void score_kernel(
    const float* __restrict__ z, const float* __restrict__ seq_mask,
    const float* __restrict__ z_ln_w, const float* __restrict__ z_ln_b,
    const float* __restrict__ z_w,
    const float* __restrict__ Q, const float* __restrict__ K,
    float* __restrict__ scores)
{
    const int b = blockIdx.x;
    const int q = b >> 3;
    const int j0 = (b & 7) * 64;
    const int tid = threadIdx.x;
    const int w = tid >> 6;        // wave id -> channel slice
    const int lane = tid & 63;     // key row within tile

    __shared__ float a_s[H][CZ + 4];      // folded lnw*zw        8.4 KB
    __shared__ float AhBh[2][H];          //                      128 B
    __shared__ float qrow[DS];            //                      1.5 KB
    __shared__ float stats[4][2][68];     // [wave][sum/sq][row]  2.2 KB
    __shared__ float opart[4][H][68];     // [wave][head][row]    17.4 KB
    __shared__ float buf[H][68];          // output transpose     4.3 KB

    // ---- Phase 0: stage a_s (+Ah/Bh) and qrow ----
    {
        const int h = tid >> 4;           // 0..15
        const int c8 = (tid & 15) * 8;    // 8 channels each
        float A = 0.f, Bv = 0.f;
#pragma unroll
        for (int p = 0; p < 2; ++p) {
            float4 wz = *(const float4*)(z_w + h * CZ + c8 + p * 4);
            float4 lw = *(const float4*)(z_ln_w + c8 + p * 4);
            float4 lb = *(const float4*)(z_ln_b + c8 + p * 4);
            float4 a;
            a.x = lw.x * wz.x; a.y = lw.y * wz.y; a.z = lw.z * wz.z; a.w = lw.w * wz.w;
            *(float4*)&a_s[h][c8 + p * 4] = a;
            A += a.x + a.y + a.z + a.w;
            Bv += lb.x * wz.x + lb.y * wz.y + lb.z * wz.z + lb.w * wz.w;
        }
#pragma unroll
        for (int m = 1; m < 16; m <<= 1) {
            A += __shfl_xor(A, m);
            Bv += __shfl_xor(Bv, m);
        }
        if ((tid & 15) == 0) { AhBh[0][h] = A; AhBh[1][h] = Bv; }
    }
    for (int i = tid; i < DS; i += 256) qrow[i] = Q[q * DS + i];
    __syncthreads();

    // ---- Phase 1: per-wave partial GEMM over its 32-channel slice ----
    {
        const int c0 = w * 32;
        const float* zr = z + ((long)q * S + j0 + lane) * CZ + c0;
        float4 zf[8];
#pragma unroll
        for (int t = 0; t < 8; ++t) zf[t] = *(const float4*)(zr + t * 4);

        float s1 = 0.f, s2 = 0.f;
#pragma unroll
        for (int t = 0; t < 8; ++t) {
            s1 += zf[t].x + zf[t].y + zf[t].z + zf[t].w;
            s2 += zf[t].x * zf[t].x + zf[t].y * zf[t].y + zf[t].z * zf[t].z + zf[t].w * zf[t].w;
        }
        stats[w][0][lane] = s1;
        stats[w][1][lane] = s2;

#pragma unroll
        for (int h = 0; h < H; ++h) {
            float acc = 0.f;
#pragma unroll
            for (int t = 0; t < 8; ++t) {
                float4 a4 = *(const float4*)&a_s[h][c0 + t * 4];   // wave-uniform: broadcast
                acc += zf[t].x * a4.x + zf[t].y * a4.y + zf[t].z * a4.z + zf[t].w * a4.w;
            }
            opart[w][h][lane] = acc;
        }
    }
    __syncthreads();

    // ---- Phase 2: combine partials, LN affine + QK, write via transpose buffer ----
    {
        const int r = tid >> 2;           // key row 0..63
        const int hq = tid & 3;           // head quad
        float s1 = stats[0][0][r] + stats[1][0][r] + stats[2][0][r] + stats[3][0][r];
        float s2 = stats[0][1][r] + stats[1][1][r] + stats[2][1][r] + stats[3][1][r];
        const float mu = s1 * (1.f / 128.f);
        const float rs = rsqrtf(s2 * (1.f / 128.f) - mu * mu + EPSV);
        const float mk = seq_mask[j0 + r];
        const float scale = 0.2041241452319315f;  // 1/sqrt(24)
        const float* krow = K + (long)(j0 + r) * DS;

#pragma unroll
        for (int i = 0; i < 4; ++i) {
            const int h = hq * 4 + i;
            float dza = opart[0][h][r] + opart[1][h][r] + opart[2][h][r] + opart[3][h][r];
            const float4* k4 = (const float4*)(krow + h * D);
            const float4* q4 = (const float4*)(qrow + h * D);
            float qk = 0.f;
#pragma unroll
            for (int t = 0; t < 6; ++t) {
                float4 kv = k4[t];
                float4 qv = q4[t];
                qk += kv.x * qv.x + kv.y * qv.y + kv.z * qv.z + kv.w * qv.w;
            }
            const float bias = rs * dza - mu * rs * AhBh[0][h] + AhBh[1][h];
            buf[h][r] = qk * scale + bias + mk;
        }
    }
    __syncthreads();

    // coalesced store: 16 threads per head, float4 along j
    {
        const int h = tid >> 4, j4 = tid & 15;
        float4 v = *(const float4*)&buf[h][j4 * 4];
        *(float4*)(scores + ((q << 4) + h) * S + j0 + j4 * 4) = v;
    }
}

// ================= Kernel 2b: softmax + PV + gate, COALESCED V =================
__global__ __launch_bounds__(256) void spv_kernel(
    const float* __restrict__ scores, const float* __restrict__ V,
    const float* __restrict__ G, float* __restrict__ og)
{
    const int q = blockIdx.x;
    const int tid = threadIdx.x;
    const int wv = tid >> 6;
    const int lane = tid & 63;

    __shared__ float sc[H][S + 4];
    __shared__ float opart[4][DS];
    __shared__ float inv_l[H];

    for (int i = tid; i < H * (S / 4); i += 256) {
        int row = i >> 7, f4 = i & 127;
        float4 v = ((const float4*)(scores + ((q << 4) + row) * S))[f4];
        *(float4*)&sc[row][f4 * 4] = v;
    }
    __syncthreads();

#pragma unroll
    for (int i = 0; i < 4; ++i) {
        int h = wv * 4 + i;
        float m = -1e30f;
        for (int j = lane; j < S; j += 64) m = fmaxf(m, sc[h][j]);
#pragma unroll
        for (int mk = 1; mk < 64; mk <<= 1) m = fmaxf(m, __shfl_xor(m, mk));
        float sum = 0.f;
        for (int j = lane; j < S; j += 64) {
            float p = __expf(sc[h][j] - m);
            sc[h][j] = p;
            sum += p;
        }
#pragma unroll
        for (int mk = 1; mk < 64; mk <<= 1) sum += __shfl_xor(sum, mk);
        if (lane == 0) inv_l[h] = 1.f / sum;
    }
    __syncthreads();

    // ---- PV: wave wv -> j in [wv*128, wv*128+128); lane -> c0 = lane*4 (+ c1 for lane<32)
    {
        const int jb = wv * 128;
        const int c0 = lane * 4;
        const int h0 = c0 / 24;
        const int c1 = 256 + lane * 4;            // only lanes 0..31
        const int h1 = c1 / 24;                   // <=15 for lane<32
        float4 a0 = {0.f, 0.f, 0.f, 0.f};
        float4 a1 = {0.f, 0.f, 0.f, 0.f};
#pragma unroll 4
        for (int jj = 0; jj < 128; ++jj) {
            const int j = jb + jj;
            const float4* vr = (const float4*)(V + (long)j * DS);
            const float p0 = sc[h0][j];
            float4 v0 = vr[lane];
            a0.x += p0 * v0.x; a0.y += p0 * v0.y; a0.z += p0 * v0.z; a0.w += p0 * v0.w;
            if (lane < 32) {
                const float p1 = sc[h1][j];
                float4 v1 = vr[64 + lane];
                a1.x += p1 * v1.x; a1.y += p1 * v1.y; a1.z += p1 * v1.z; a1.w += p1 * v1.w;
            }
        }
        *(float4*)&opart[wv][c0] = a0;
        if (lane < 32) *(float4*)&opart[wv][c1] = a1;
    }
    __syncthreads();
    for (int i = tid; i < DS; i += 256) {
        float o = opart[0][i] + opart[1][i] + opart[2][i] + opart[3][i];
        int h = i / 24;
        og[q * DS + i] = o * inv_l[h] * G[q * DS + i];
    }
}

// ================= Kernel 3: tiled output projection (baseline, passing) =================
__global__ __launch_bounds__(256) void out_kernel(
    const float* __restrict__ og, const float* __restrict__ o_w, float* __restrict__ out)
{
    const int b = blockIdx.x;
    const int by = b / 6, bx = b % 6;

    __shared__ float As[32][68];
    __shared__ float Ws[32][68];

    const int tid = threadIdx.x;
    const int tx = tid & 15, ty = tid >> 4;
    const int r8 = tid >> 3;
    const int c4 = tid & 7;

    float acc[4][4] = {};
    for (int kc = 0; kc < DS; kc += 32) {
        __syncthreads();
#pragma unroll
        for (int pass = 0; pass < 2; ++pass) {
            int r = r8 + pass * 32;
            float4 sv = *(const float4*)(og + (by * 64 + r) * DS + kc + c4 * 4);
            float4 wvv = *(const float4*)(o_w + (bx * 64 + r) * DS + kc + c4 * 4);
            As[c4 * 4 + 0][r] = sv.x; As[c4 * 4 + 1][r] = sv.y;
            As[c4 * 4 + 2][r] = sv.z; As[c4 * 4 + 3][r] = sv.w;
            Ws[c4 * 4 + 0][r] = wvv.x; Ws[c4 * 4 + 1][r] = wvv.y;
            Ws[c4 * 4 + 2][r] = wvv.z; Ws[c4 * 4 + 3][r] = wvv.w;
        }
        __syncthreads();
#pragma unroll
        for (int k = 0; k < 32; ++k) {
            float4 a4 = *(const float4*)&As[k][ty * 4];
            float4 b4 = *(const float4*)&Ws[k][tx * 4];
            acc[0][0] += a4.x * b4.x; acc[0][1] += a4.x * b4.y; acc[0][2] += a4.x * b4.z; acc[0][3] += a4.x * b4.w;
            acc[1][0] += a4.y * b4.x; acc[1][1] += a4.y * b4.y; acc[1][2] += a4.y * b4.z; acc[1][3] += a4.y * b4.w;
            acc[2][0] += a4.z * b4.x; acc[2][1] += a4.z * b4.y; acc[2][2] += a4.z * b4.z; acc[2][3] += a4.z * b4.w;
            acc[3][0] += a4.w * b4.x; acc[3][1] += a4.w * b4.y; acc[3][2] += a4.w * b4.z; acc[3][3] += a4.w * b4.w;
        }
    }

    const int r0 = by * 64 + ty * 4;
    const int c0 = bx * 64 + tx * 4;
#pragma unroll
    for (int ii = 0; ii < 4; ++ii) {
        float4 v;
        v.x = acc[ii][0]; v.y = acc[ii][1]; v.z = acc[ii][2]; v.w = acc[ii][3];
        *(float4*)(out + (r0 + ii) * DS + c0) = v;
    }
}

extern "C" void kernel_launch(void* const* d_in, const int* in_sizes, int n_in,
                              void* d_out, int out_size, void* d_ws, size_t ws_size,
                              hipStream_t stream)
{
    const float* s      = (const float*)d_in[0];
    const float* z      = (const float*)d_in[1];
    const float* mask   = (const float*)d_in[2];
    const float* q_w    = (const float*)d_in[3];
    const float* q_b    = (const float*)d_in[4];
    const float* k_w    = (const float*)d_in[5];
    const float* v_w    = (const float*)d_in[6];
    const float* g_w    = (const float*)d_in[7];
    const float* o_w    = (const float*)d_in[8];
    const float* z_ln_w = (const float*)d_in[9];
    const float* z_ln_b = (const float*)d_in[10];
    const float* z_w    = (const float*)d_in[11];

    float* Q  = (float*)d_ws;
    float* K  = Q + S * DS;
    float* V  = K + S * DS;                 // natural [S][H*D] layout
    float* G  = V + S * DS;
    float* og = G + S * DS;
    float* scores = og + S * DS;            // H*S*S floats = 16.8 MB

    hipLaunchKernelGGL(proj_kernel, dim3(192), dim3(256), 0, stream,
                       s, q_w, q_b, k_w, v_w, g_w, Q, K, V, G);
    hipLaunchKernelGGL(score_kernel, dim3(4096), dim3(256), 0, stream,
                       z, mask, z_ln_w, z_ln_b, z_w, Q, K, scores);
    hipLaunchKernelGGL(spv_kernel, dim3(S), dim3(256), 0, stream,
                       scores, V, G, og);
    hipLaunchKernelGGL(out_kernel, dim3(48), dim3(256), 0, stream,
                       og, o_w, (float*)d_out);
}

// Round 12
// 331.449 us; speedup vs baseline: 1.1580x; 1.0184x over previous
//
#include <hip/hip_runtime.h>

#define H 16
#define D 24
#define DS 384
#define CZ 128
#define S 512
#define EPSV 1e-5f

// ================= Kernel 1: tiled Q/K/V/G projections (r11, passing) =================
__global__ __launch_bounds__(256) void proj_kernel(
    const float* __restrict__ s, const float* __restrict__ q_w, const float* __restrict__ q_b,
    const float* __restrict__ k_w, const float* __restrict__ v_w, const float* __restrict__ g_w,
    float* __restrict__ Q, float* __restrict__ K, float* __restrict__ V, float* __restrict__ G)
{
    const int b = blockIdx.x;
    const int mat = b / 48;          // 0:Q 1:K 2:V 3:G
    const int t = b % 48;
    const int by = t / 6, bx = t % 6;
    const float* w = (mat == 0) ? q_w : (mat == 1) ? k_w : (mat == 2) ? v_w : g_w;

    __shared__ float As[32][68];
    __shared__ float Ws[32][68];

    const int tid = threadIdx.x;
    const int tx = tid & 15, ty = tid >> 4;
    const int r8 = tid >> 3;
    const int c4 = tid & 7;

    float acc[4][4] = {};
    for (int kc = 0; kc < DS; kc += 32) {
        __syncthreads();
#pragma unroll
        for (int pass = 0; pass < 2; ++pass) {
            int r = r8 + pass * 32;
            float4 sv = *(const float4*)(s + (by * 64 + r) * DS + kc + c4 * 4);
            float4 wv = *(const float4*)(w + (bx * 64 + r) * DS + kc + c4 * 4);
            As[c4 * 4 + 0][r] = sv.x; As[c4 * 4 + 1][r] = sv.y;
            As[c4 * 4 + 2][r] = sv.z; As[c4 * 4 + 3][r] = sv.w;
            Ws[c4 * 4 + 0][r] = wv.x; Ws[c4 * 4 + 1][r] = wv.y;
            Ws[c4 * 4 + 2][r] = wv.z; Ws[c4 * 4 + 3][r] = wv.w;
        }
        __syncthreads();
#pragma unroll
        for (int k = 0; k < 32; ++k) {
            float4 a4 = *(const float4*)&As[k][ty * 4];
            float4 b4 = *(const float4*)&Ws[k][tx * 4];
            acc[0][0] += a4.x * b4.x; acc[0][1] += a4.x * b4.y; acc[0][2] += a4.x * b4.z; acc[0][3] += a4.x * b4.w;
            acc[1][0] += a4.y * b4.x; acc[1][1] += a4.y * b4.y; acc[1][2] += a4.y * b4.z; acc[1][3] += a4.y * b4.w;
            acc[2][0] += a4.z * b4.x; acc[2][1] += a4.z * b4.y; acc[2][2] += a4.z * b4.z; acc[2][3] += a4.z * b4.w;
            acc[3][0] += a4.w * b4.x; acc[3][1] += a4.w * b4.y; acc[3][2] += a4.w * b4.z; acc[3][3] += a4.w * b4.w;
        }
    }

    const int r0 = by * 64 + ty * 4;
    const int c0 = bx * 64 + tx * 4;
    float* dst = (mat == 0) ? Q : (mat == 1) ? K : (mat == 2) ? V : G;
#pragma unroll
    for (int ii = 0; ii < 4; ++ii) {
        float4 v;
        v.x = acc[ii][0]; v.y = acc[ii][1]; v.z = acc[ii][2]; v.w = acc[ii][3];
        if (mat == 0) {
            v.x += q_b[c0 + 0]; v.y += q_b[c0 + 1]; v.z += q_b[c0 + 2]; v.w += q_b[c0 + 3];
        } else if (mat == 3) {
            v.x = 1.f / (1.f + __expf(-v.x)); v.y = 1.f / (1.f + __expf(-v.y));
            v.z = 1.f / (1.f + __expf(-v.z)); v.w = 1.f / (1.f + __expf(-v.w));
        }
        *(float4*)(dst + (r0 + ii) * DS + c0) = v;
    }
}

// ================= Kernel 2a: r3 structure + chunk-staged K (TA-request fix) =================
// Phases 0/1 identical to the 97us r3 kernel. The ONLY change: phase-2's per-lane K gather
// (24 instr/thread x 64 distinct lines/instr = 6144 addr-transactions/block, ~41us/CU of
// TA serialization -- the invariant cost across r3..r9) is replaced by 8-row chunked LDS
// staging: contiguous 12KB loads (8 lines/wave-inst, 768 requests total), dots from LDS
// with stride-388 rows (start-quads uniform mod 8 -> optimal b128), Q-frags hoisted to
// registers. qk math bit-identical. buf aliases dead Ks; LDS 45.4 KB -> 3 blocks/CU kept.
__global__ __launch_bounds__(256) void score_kernel(
    const float* __restrict__ z, const float* __restrict__ seq_mask,
    const float* __restrict__ z_ln_w, const float* __restrict__ z_ln_b,
    const float* __restrict__ z_w,
    const float* __restrict__ Q, const float* __restrict__ K,
    float* __restrict__ scores)
{
    const int b = blockIdx.x;
    const int q = b >> 3;
    const int j0 = (b & 7) * 64;
    const int tid = threadIdx.x;
    const int w = tid >> 6;        // wave id -> channel slice
    const int lane = tid & 63;     // key row within tile

    __shared__ float a_s[H][CZ + 4];      // folded lnw*zw        8.4 KB
    __shared__ float AhBh[2][H];          //                      128 B
    __shared__ float qrow[DS];            //                      1.5 KB
    __shared__ float stats[4][2][68];     // [wave][sum/sq][row]  2.2 KB
    __shared__ float opart[4][H][68];     // [wave][head][row]    17.4 KB
    __shared__ float Ks[8 * 388];         // K chunk (8 rows)     12.1 KB (buf aliases)
    __shared__ float qks[H][68];          // qk results           4.3 KB

    // ---- Phase 0: stage a_s (+Ah/Bh) and qrow ----
    {
        const int h = tid >> 4;           // 0..15
        const int c8 = (tid & 15) * 8;    // 8 channels each
        float A = 0.f, Bv = 0.f;
#pragma unroll
        for (int p = 0; p < 2; ++p) {
            float4 wz = *(const float4*)(z_w + h * CZ + c8 + p * 4);
            float4 lw = *(const float4*)(z_ln_w + c8 + p * 4);
            float4 lb = *(const float4*)(z_ln_b + c8 + p * 4);
            float4 a;
            a.x = lw.x * wz.x; a.y = lw.y * wz.y; a.z = lw.z * wz.z; a.w = lw.w * wz.w;
            *(float4*)&a_s[h][c8 + p * 4] = a;
            A += a.x + a.y + a.z + a.w;
            Bv += lb.x * wz.x + lb.y * wz.y + lb.z * wz.z + lb.w * wz.w;
        }
#pragma unroll
        for (int m = 1; m < 16; m <<= 1) {
            A += __shfl_xor(A, m);
            Bv += __shfl_xor(Bv, m);
        }
        if ((tid & 15) == 0) { AhBh[0][h] = A; AhBh[1][h] = Bv; }
    }
    for (int i = tid; i < DS; i += 256) qrow[i] = Q[q * DS + i];
    __syncthreads();

    // Q fragment for the dot phase: thread (tid<128) owns head tid&15, hoisted once.
    float4 qreg[6];
    if (tid < 128) {
        const int h = tid & 15;
#pragma unroll
        for (int t = 0; t < 6; ++t) qreg[t] = *(const float4*)&qrow[h * 24 + t * 4];
    }

    // ---- Phase 1: per-wave partial GEMM over its 32-channel slice (unchanged) ----
    {
        const int c0 = w * 32;
        const float* zr = z + ((long)q * S + j0 + lane) * CZ + c0;
        float4 zf[8];
#pragma unroll
        for (int t = 0; t < 8; ++t) zf[t] = *(const float4*)(zr + t * 4);

        float s1 = 0.f, s2 = 0.f;
#pragma unroll
        for (int t = 0; t < 8; ++t) {
            s1 += zf[t].x + zf[t].y + zf[t].z + zf[t].w;
            s2 += zf[t].x * zf[t].x + zf[t].y * zf[t].y + zf[t].z * zf[t].z + zf[t].w * zf[t].w;
        }
        stats[w][0][lane] = s1;
        stats[w][1][lane] = s2;

#pragma unroll
        for (int h = 0; h < H; ++h) {
            float acc = 0.f;
#pragma unroll
            for (int t = 0; t < 8; ++t) {
                float4 a4 = *(const float4*)&a_s[h][c0 + t * 4];   // wave-uniform: broadcast
                acc += zf[t].x * a4.x + zf[t].y * a4.y + zf[t].z * a4.z + zf[t].w * a4.w;
            }
            opart[w][h][lane] = acc;
        }
    }
    __syncthreads();

    // ---- K chunks: stage 8 contiguous rows coalesced, dot per (row, head) ----
    for (int c = 0; c < 8; ++c) {
        const float* kc = K + (long)(j0 + c * 8) * DS;   // 8 rows = contiguous 12 KB
#pragma unroll
        for (int it = 0; it < 3; ++it) {
            const int idx = it * 256 + tid;              // 0..767 float4
            const int row8 = idx / 96, col = idx - row8 * 96;
            float4 v = *(const float4*)(kc + idx * 4);   // fully contiguous global load
            *(float4*)&Ks[row8 * 388 + col * 4] = v;
        }
        __syncthreads();
        if (tid < 128) {
            const int r8 = tid >> 4, h = tid & 15;
            const float4* kk = (const float4*)&Ks[r8 * 388 + h * 24];
            float qk = 0.f;
#pragma unroll
            for (int t = 0; t < 6; ++t) {
                float4 kv = kk[t];
                float4 qv = qreg[t];
                qk += kv.x * qv.x + kv.y * qv.y + kv.z * qv.z + kv.w * qv.w;
            }
            qks[h][c * 8 + r8] = qk;
        }
        __syncthreads();
    }

    // ---- Phase 2: combine partials, LN affine + qk (from LDS), write transpose buffer ----
    float (*buf)[68] = (float (*)[68])Ks;   // Ks dead after last chunk barrier
    {
        const int r = tid >> 2;           // key row 0..63
        const int hq = tid & 3;           // head quad
        float s1 = stats[0][0][r] + stats[1][0][r] + stats[2][0][r] + stats[3][0][r];
        float s2 = stats[0][1][r] + stats[1][1][r] + stats[2][1][r] + stats[3][1][r];
        const float mu = s1 * (1.f / 128.f);
        const float rs = rsqrtf(s2 * (1.f / 128.f) - mu * mu + EPSV);
        const float mk = seq_mask[j0 + r];
        const float scale = 0.2041241452319315f;  // 1/sqrt(24)

#pragma unroll
        for (int i = 0; i < 4; ++i) {
            const int h = hq * 4 + i;
            float dza = opart[0][h][r] + opart[1][h][r] + opart[2][h][r] + opart[3][h][r];
            const float qk = qks[h][r];
            const float bias = rs * dza - mu * rs * AhBh[0][h] + AhBh[1][h];
            buf[h][r] = qk * scale + bias + mk;
        }
    }
    __syncthreads();

    // coalesced store: 16 threads per head, float4 along j
    {
        const int h = tid >> 4, j4 = tid & 15;
        float4 v = *(const float4*)&buf[h][j4 * 4];
        *(float4*)(scores + ((q << 4) + h) * S + j0 + j4 * 4) = v;
    }
}

// ================= Kernel 2b: softmax + PV + gate, coalesced V (r11, passing) =================
__global__ __launch_bounds__(256) void spv_kernel(
    const float* __restrict__ scores, const float* __restrict__ V,
    const float* __restrict__ G, float* __restrict__ og)
{
    const int q = blockIdx.x;
    const int tid = threadIdx.x;
    const int wv = tid >> 6;
    const int lane = tid & 63;

    __shared__ float sc[H][S + 4];
    __shared__ float opart[4][DS];
    __shared__ float inv_l[H];

    for (int i = tid; i < H * (S / 4); i += 256) {
        int row = i >> 7, f4 = i & 127;
        float4 v = ((const float4*)(scores + ((q << 4) + row) * S))[f4];
        *(float4*)&sc[row][f4 * 4] = v;
    }
    __syncthreads();

#pragma unroll
    for (int i = 0; i < 4; ++i) {
        int h = wv * 4 + i;
        float m = -1e30f;
        for (int j = lane; j < S; j += 64) m = fmaxf(m, sc[h][j]);
#pragma unroll
        for (int mk = 1; mk < 64; mk <<= 1) m = fmaxf(m, __shfl_xor(m, mk));
        float sum = 0.f;
        for (int j = lane; j < S; j += 64) {
            float p = __expf(sc[h][j] - m);
            sc[h][j] = p;
            sum += p;
        }
#pragma unroll
        for (int mk = 1; mk < 64; mk <<= 1) sum += __shfl_xor(sum, mk);
        if (lane == 0) inv_l[h] = 1.f / sum;
    }
    __syncthreads();

    // ---- PV: wave wv -> j in [wv*128, wv*128+128); lane -> c0 = lane*4 (+ c1 for lane<32)
    {
        const int jb = wv * 128;
        const int c0 = lane * 4;
        const int h0 = c0 / 24;
        const int c1 = 256 + lane * 4;            // only lanes 0..31
        const int h1 = c1 / 24;                   // <=15 for lane<32
        float4 a0 = {0.f, 0.f, 0.f, 0.f};
        float4 a1 = {0.f, 0.f, 0.f, 0.f};
#pragma unroll 4
        for (int jj = 0; jj < 128; ++jj) {
            const int j = jb + jj;
            const float4* vr = (const float4*)(V + (long)j * DS);
            const float p0 = sc[h0][j];
            float4 v0 = vr[lane];
            a0.x += p0 * v0.x; a0.y += p0 * v0.y; a0.z += p0 * v0.z; a0.w += p0 * v0.w;
            if (lane < 32) {
                const float p1 = sc[h1][j];
                float4 v1 = vr[64 + lane];
                a1.x += p1 * v1.x; a1.y += p1 * v1.y; a1.z += p1 * v1.z; a1.w += p1 * v1.w;
            }
        }
        *(float4*)&opart[wv][c0] = a0;
        if (lane < 32) *(float4*)&opart[wv][c1] = a1;
    }
    __syncthreads();
    for (int i = tid; i < DS; i += 256) {
        float o = opart[0][i] + opart[1][i] + opart[2][i] + opart[3][i];
        int h = i / 24;
        og[q * DS + i] = o * inv_l[h] * G[q * DS + i];
    }
}

// ================= Kernel 3: tiled output projection (r11, passing) =================
__global__ __launch_bounds__(256) void out_kernel(
    const float* __restrict__ og, const float* __restrict__ o_w, float* __restrict__ out)
{
    const int b = blockIdx.x;
    const int by = b / 6, bx = b % 6;

    __shared__ float As[32][68];
    __shared__ float Ws[32][68];

    const int tid = threadIdx.x;
    const int tx = tid & 15, ty = tid >> 4;
    const int r8 = tid >> 3;
    const int c4 = tid & 7;

    float acc[4][4] = {};
    for (int kc = 0; kc < DS; kc += 32) {
        __syncthreads();
#pragma unroll
        for (int pass = 0; pass < 2; ++pass) {
            int r = r8 + pass * 32;
            float4 sv = *(const float4*)(og + (by * 64 + r) * DS + kc + c4 * 4);
            float4 wvv = *(const float4*)(o_w + (bx * 64 + r) * DS + kc + c4 * 4);
            As[c4 * 4 + 0][r] = sv.x; As[c4 * 4 + 1][r] = sv.y;
            As[c4 * 4 + 2][r] = sv.z; As[c4 * 4 + 3][r] = sv.w;
            Ws[c4 * 4 + 0][r] = wvv.x; Ws[c4 * 4 + 1][r] = wvv.y;
            Ws[c4 * 4 + 2][r] = wvv.z; Ws[c4 * 4 + 3][r] = wvv.w;
        }
        __syncthreads();
#pragma unroll
        for (int k = 0; k < 32; ++k) {
            float4 a4 = *(const float4*)&As[k][ty * 4];
            float4 b4 = *(const float4*)&Ws[k][tx * 4];
            acc[0][0] += a4.x * b4.x; acc[0][1] += a4.x * b4.y; acc[0][2] += a4.x * b4.z; acc[0][3] += a4.x * b4.w;
            acc[1][0] += a4.y * b4.x; acc[1][1] += a4.y * b4.y; acc[1][2] += a4.y * b4.z; acc[1][3] += a4.y * b4.w;
            acc[2][0] += a4.z * b4.x; acc[2][1] += a4.z * b4.y; acc[2][2] += a4.z * b4.z; acc[2][3] += a4.z * b4.w;
            acc[3][0] += a4.w * b4.x; acc[3][1] += a4.w * b4.y; acc[3][2] += a4.w * b4.z; acc[3][3] += a4.w * b4.w;
        }
    }

    const int r0 = by * 64 + ty * 4;
    const int c0 = bx * 64 + tx * 4;
#pragma unroll
    for (int ii = 0; ii < 4; ++ii) {
        float4 v;
        v.x = acc[ii][0]; v.y = acc[ii][1]; v.z = acc[ii][2]; v.w = acc[ii][3];
        *(float4*)(out + (r0 + ii) * DS + c0) = v;
    }
}

extern "C" void kernel_launch(void* const* d_in, const int* in_sizes, int n_in,
                              void* d_out, int out_size, void* d_ws, size_t ws_size,
                              hipStream_t stream)
{
    const float* s      = (const float*)d_in[0];
    const float* z      = (const float*)d_in[1];
    const float* mask   = (const float*)d_in[2];
    const float* q_w    = (const float*)d_in[3];
    const float* q_b    = (const float*)d_in[4];
    const float* k_w    = (const float*)d_in[5];
    const float* v_w    = (const float*)d_in[6];
    const float* g_w    = (const float*)d_in[7];
    const float* o_w    = (const float*)d_in[8];
    const float* z_ln_w = (const float*)d_in[9];
    const float* z_ln_b = (const float*)d_in[10];
    const float* z_w    = (const float*)d_in[11];

    float* Q  = (float*)d_ws;
    float* K  = Q + S * DS;
    float* V  = K + S * DS;                 // natural [S][H*D] layout
    float* G  = V + S * DS;
    float* og = G + S * DS;
    float* scores = og + S * DS;            // H*S*S floats = 16.8 MB

    hipLaunchKernelGGL(proj_kernel, dim3(192), dim3(256), 0, stream,
                       s, q_w, q_b, k_w, v_w, g_w, Q, K, V, G);
    hipLaunchKernelGGL(score_kernel, dim3(4096), dim3(256), 0, stream,
                       z, mask, z_ln_w, z_ln_b, z_w, Q, K, scores);
    hipLaunchKernelGGL(spv_kernel, dim3(S), dim3(256), 0, stream,
                       scores, V, G, og);
    hipLaunchKernelGGL(out_kernel, dim3(48), dim3(256), 0, stream,
                       og, o_w, (float*)d_out);
}

// Round 13
// 320.500 us; speedup vs baseline: 1.1975x; 1.0342x over previous
//
#include <hip/hip_runtime.h>

#define H 16
#define D 24
#define DS 384
#define CZ 128
#define S 512
#define EPSV 1e-5f

// ================= Kernel 1: tiled Q/K/V/G projections (r11, passing) =================
__global__ __launch_bounds__(256) void proj_kernel(
    const float* __restrict__ s, const float* __restrict__ q_w, const float* __restrict__ q_b,
    const float* __restrict__ k_w, const float* __restrict__ v_w, const float* __restrict__ g_w,
    float* __restrict__ Q, float* __restrict__ K, float* __restrict__ V, float* __restrict__ G)
{
    const int b = blockIdx.x;
    const int mat = b / 48;          // 0:Q 1:K 2:V 3:G
    const int t = b % 48;
    const int by = t / 6, bx = t % 6;
    const float* w = (mat == 0) ? q_w : (mat == 1) ? k_w : (mat == 2) ? v_w : g_w;

    __shared__ float As[32][68];
    __shared__ float Ws[32][68];

    const int tid = threadIdx.x;
    const int tx = tid & 15, ty = tid >> 4;
    const int r8 = tid >> 3;
    const int c4 = tid & 7;

    float acc[4][4] = {};
    for (int kc = 0; kc < DS; kc += 32) {
        __syncthreads();
#pragma unroll
        for (int pass = 0; pass < 2; ++pass) {
            int r = r8 + pass * 32;
            float4 sv = *(const float4*)(s + (by * 64 + r) * DS + kc + c4 * 4);
            float4 wv = *(const float4*)(w + (bx * 64 + r) * DS + kc + c4 * 4);
            As[c4 * 4 + 0][r] = sv.x; As[c4 * 4 + 1][r] = sv.y;
            As[c4 * 4 + 2][r] = sv.z; As[c4 * 4 + 3][r] = sv.w;
            Ws[c4 * 4 + 0][r] = wv.x; Ws[c4 * 4 + 1][r] = wv.y;
            Ws[c4 * 4 + 2][r] = wv.z; Ws[c4 * 4 + 3][r] = wv.w;
        }
        __syncthreads();
#pragma unroll
        for (int k = 0; k < 32; ++k) {
            float4 a4 = *(const float4*)&As[k][ty * 4];
            float4 b4 = *(const float4*)&Ws[k][tx * 4];
            acc[0][0] += a4.x * b4.x; acc[0][1] += a4.x * b4.y; acc[0][2] += a4.x * b4.z; acc[0][3] += a4.x * b4.w;
            acc[1][0] += a4.y * b4.x; acc[1][1] += a4.y * b4.y; acc[1][2] += a4.y * b4.z; acc[1][3] += a4.y * b4.w;
            acc[2][0] += a4.z * b4.x; acc[2][1] += a4.z * b4.y; acc[2][2] += a4.z * b4.z; acc[2][3] += a4.z * b4.w;
            acc[3][0] += a4.w * b4.x; acc[3][1] += a4.w * b4.y; acc[3][2] += a4.w * b4.z; acc[3][3] += a4.w * b4.w;
        }
    }

    const int r0 = by * 64 + ty * 4;
    const int c0 = bx * 64 + tx * 4;
    float* dst = (mat == 0) ? Q : (mat == 1) ? K : (mat == 2) ? V : G;
#pragma unroll
    for (int ii = 0; ii < 4; ++ii) {
        float4 v;
        v.x = acc[ii][0]; v.y = acc[ii][1]; v.z = acc[ii][2]; v.w = acc[ii][3];
        if (mat == 0) {
            v.x += q_b[c0 + 0]; v.y += q_b[c0 + 1]; v.z += q_b[c0 + 2]; v.w += q_b[c0 + 3];
        } else if (mat == 3) {
            v.x = 1.f / (1.f + __expf(-v.x)); v.y = 1.f / (1.f + __expf(-v.y));
            v.z = 1.f / (1.f + __expf(-v.z)); v.w = 1.f / (1.f + __expf(-v.w));
        }
        *(float4*)(dst + (r0 + ii) * DS + c0) = v;
    }
}

// ================= Kernel 2a: r12 structure, LDS-liveness-packed =================
// Same access patterns as r12 (88us measured): a-broadcast, lane-private z lines,
// contiguous 8-row K staging, stride-388 LDS dots. Changes (liveness only):
//  - K-dot phase moved BEFORE the z GEMM -> Ks / opart / buf share ONE 17.4KB union
//    (Ks dead before opart written; each buf[h][r] written only by the thread that
//    read opart[*][h][r] -- no cross-thread hazard).
//  - qrow deleted (Q-frags hoisted straight from global; phase 2 uses qks only).
// LDS 46.6 -> 31.8 KB => 5 blocks/CU, 20 waves/CU (was 3 blocks / 12 waves).
__global__ __launch_bounds__(256) void score_kernel(
    const float* __restrict__ z, const float* __restrict__ seq_mask,
    const float* __restrict__ z_ln_w, const float* __restrict__ z_ln_b,
    const float* __restrict__ z_w,
    const float* __restrict__ Q, const float* __restrict__ K,
    float* __restrict__ scores)
{
    const int b = blockIdx.x;
    const int q = b >> 3;
    const int j0 = (b & 7) * 64;
    const int tid = threadIdx.x;
    const int w = tid >> 6;        // wave id -> channel slice
    const int lane = tid & 63;     // key row within tile

    __shared__ float a_s[H][CZ + 4];      // folded lnw*zw        8.4 KB
    __shared__ float AhBh[2][H];          //                      128 B
    __shared__ float stats[4][2][68];     // [wave][sum/sq][row]  2.2 KB
    __shared__ float qks[H][68];          // qk results           4.3 KB
    __shared__ float uni[4 * H * 68];     // Ks | opart | buf     17.4 KB (time-shared)

    float* Ks = uni;                              // 8*388 = 3104 floats
    float (*opart)[H][68] = (float (*)[H][68])uni;
    float (*buf)[68] = (float (*)[68])uni;

    // ---- Phase 0: stage a_s (+Ah/Bh); hoist Q-fragment from global ----
    {
        const int h = tid >> 4;           // 0..15
        const int c8 = (tid & 15) * 8;    // 8 channels each
        float A = 0.f, Bv = 0.f;
#pragma unroll
        for (int p = 0; p < 2; ++p) {
            float4 wz = *(const float4*)(z_w + h * CZ + c8 + p * 4);
            float4 lw = *(const float4*)(z_ln_w + c8 + p * 4);
            float4 lb = *(const float4*)(z_ln_b + c8 + p * 4);
            float4 a;
            a.x = lw.x * wz.x; a.y = lw.y * wz.y; a.z = lw.z * wz.z; a.w = lw.w * wz.w;
            *(float4*)&a_s[h][c8 + p * 4] = a;
            A += a.x + a.y + a.z + a.w;
            Bv += lb.x * wz.x + lb.y * wz.y + lb.z * wz.z + lb.w * wz.w;
        }
#pragma unroll
        for (int m = 1; m < 16; m <<= 1) {
            A += __shfl_xor(A, m);
            Bv += __shfl_xor(Bv, m);
        }
        if ((tid & 15) == 0) { AhBh[0][h] = A; AhBh[1][h] = Bv; }
    }

    float4 qreg[6];
    if (tid < 128) {
        const int h = tid & 15;
#pragma unroll
        for (int t = 0; t < 6; ++t)
            qreg[t] = *(const float4*)(Q + q * DS + h * 24 + t * 4);
    }

    // ---- K chunks FIRST: stage 8 contiguous rows coalesced, dot per (row, head) ----
    for (int c = 0; c < 8; ++c) {
        const float* kc = K + (long)(j0 + c * 8) * DS;   // 8 rows = contiguous 12 KB
#pragma unroll
        for (int it = 0; it < 3; ++it) {
            const int idx = it * 256 + tid;              // 0..767 float4
            const int row8 = idx / 96, col = idx - row8 * 96;
            float4 v = *(const float4*)(kc + idx * 4);   // fully contiguous global load
            *(float4*)&Ks[row8 * 388 + col * 4] = v;
        }
        __syncthreads();   // (first iteration also covers a_s/AhBh staging)
        if (tid < 128) {
            const int r8 = tid >> 4, h = tid & 15;
            const float4* kk = (const float4*)&Ks[r8 * 388 + h * 24];
            float qk = 0.f;
#pragma unroll
            for (int t = 0; t < 6; ++t) {
                float4 kv = kk[t];
                float4 qv = qreg[t];
                qk += kv.x * qv.x + kv.y * qv.y + kv.z * qv.z + kv.w * qv.w;
            }
            qks[h][c * 8 + r8] = qk;
        }
        __syncthreads();   // Ks reads done before next stage / before opart overwrites
    }

    // ---- Phase 1: per-wave partial GEMM over its 32-channel slice (opart aliases Ks) ----
    {
        const int c0 = w * 32;
        const float* zr = z + ((long)q * S + j0 + lane) * CZ + c0;
        float4 zf[8];
#pragma unroll
        for (int t = 0; t < 8; ++t) zf[t] = *(const float4*)(zr + t * 4);

        float s1 = 0.f, s2 = 0.f;
#pragma unroll
        for (int t = 0; t < 8; ++t) {
            s1 += zf[t].x + zf[t].y + zf[t].z + zf[t].w;
            s2 += zf[t].x * zf[t].x + zf[t].y * zf[t].y + zf[t].z * zf[t].z + zf[t].w * zf[t].w;
        }
        stats[w][0][lane] = s1;
        stats[w][1][lane] = s2;

#pragma unroll
        for (int h = 0; h < H; ++h) {
            float acc = 0.f;
#pragma unroll
            for (int t = 0; t < 8; ++t) {
                float4 a4 = *(const float4*)&a_s[h][c0 + t * 4];   // wave-uniform: broadcast
                acc += zf[t].x * a4.x + zf[t].y * a4.y + zf[t].z * a4.z + zf[t].w * a4.w;
            }
            opart[w][h][lane] = acc;
        }
    }
    __syncthreads();

    // ---- Phase 2: combine partials, LN affine + qk (from qks), write buf (aliases opart) ----
    {
        const int r = tid >> 2;           // key row 0..63
        const int hq = tid & 3;           // head quad
        float s1 = stats[0][0][r] + stats[1][0][r] + stats[2][0][r] + stats[3][0][r];
        float s2 = stats[0][1][r] + stats[1][1][r] + stats[2][1][r] + stats[3][1][r];
        const float mu = s1 * (1.f / 128.f);
        const float rs = rsqrtf(s2 * (1.f / 128.f) - mu * mu + EPSV);
        const float mk = seq_mask[j0 + r];
        const float scale = 0.2041241452319315f;  // 1/sqrt(24)

        float res[4];
#pragma unroll
        for (int i = 0; i < 4; ++i) {
            const int h = hq * 4 + i;
            float dza = opart[0][h][r] + opart[1][h][r] + opart[2][h][r] + opart[3][h][r];
            const float bias = rs * dza - mu * rs * AhBh[0][h] + AhBh[1][h];
            res[i] = qks[h][r] * scale + bias + mk;
        }
        // all opart reads for this thread's (h,r) slots complete before their overwrite
#pragma unroll
        for (int i = 0; i < 4; ++i) buf[hq * 4 + i][r] = res[i];
    }
    __syncthreads();

    // coalesced store: 16 threads per head, float4 along j
    {
        const int h = tid >> 4, j4 = tid & 15;
        float4 v = *(const float4*)&buf[h][j4 * 4];
        *(float4*)(scores + ((q << 4) + h) * S + j0 + j4 * 4) = v;
    }
}

// ================= Kernel 2b: softmax + PV + gate, coalesced V (r11, passing) =================
__global__ __launch_bounds__(256) void spv_kernel(
    const float* __restrict__ scores, const float* __restrict__ V,
    const float* __restrict__ G, float* __restrict__ og)
{
    const int q = blockIdx.x;
    const int tid = threadIdx.x;
    const int wv = tid >> 6;
    const int lane = tid & 63;

    __shared__ float sc[H][S + 4];
    __shared__ float opart[4][DS];
    __shared__ float inv_l[H];

    for (int i = tid; i < H * (S / 4); i += 256) {
        int row = i >> 7, f4 = i & 127;
        float4 v = ((const float4*)(scores + ((q << 4) + row) * S))[f4];
        *(float4*)&sc[row][f4 * 4] = v;
    }
    __syncthreads();

#pragma unroll
    for (int i = 0; i < 4; ++i) {
        int h = wv * 4 + i;
        float m = -1e30f;
        for (int j = lane; j < S; j += 64) m = fmaxf(m, sc[h][j]);
#pragma unroll
        for (int mk = 1; mk < 64; mk <<= 1) m = fmaxf(m, __shfl_xor(m, mk));
        float sum = 0.f;
        for (int j = lane; j < S; j += 64) {
            float p = __expf(sc[h][j] - m);
            sc[h][j] = p;
            sum += p;
        }
#pragma unroll
        for (int mk = 1; mk < 64; mk <<= 1) sum += __shfl_xor(sum, mk);
        if (lane == 0) inv_l[h] = 1.f / sum;
    }
    __syncthreads();

    // ---- PV: wave wv -> j in [wv*128, wv*128+128); lane -> c0 = lane*4 (+ c1 for lane<32)
    {
        const int jb = wv * 128;
        const int c0 = lane * 4;
        const int h0 = c0 / 24;
        const int c1 = 256 + lane * 4;            // only lanes 0..31
        const int h1 = c1 / 24;                   // <=15 for lane<32
        float4 a0 = {0.f, 0.f, 0.f, 0.f};
        float4 a1 = {0.f, 0.f, 0.f, 0.f};
#pragma unroll 4
        for (int jj = 0; jj < 128; ++jj) {
            const int j = jb + jj;
            const float4* vr = (const float4*)(V + (long)j * DS);
            const float p0 = sc[h0][j];
            float4 v0 = vr[lane];
            a0.x += p0 * v0.x; a0.y += p0 * v0.y; a0.z += p0 * v0.z; a0.w += p0 * v0.w;
            if (lane < 32) {
                const float p1 = sc[h1][j];
                float4 v1 = vr[64 + lane];
                a1.x += p1 * v1.x; a1.y += p1 * v1.y; a1.z += p1 * v1.z; a1.w += p1 * v1.w;
            }
        }
        *(float4*)&opart[wv][c0] = a0;
        if (lane < 32) *(float4*)&opart[wv][c1] = a1;
    }
    __syncthreads();
    for (int i = tid; i < DS; i += 256) {
        float o = opart[0][i] + opart[1][i] + opart[2][i] + opart[3][i];
        int h = i / 24;
        og[q * DS + i] = o * inv_l[h] * G[q * DS + i];
    }
}

// ================= Kernel 3: tiled output projection (r11, passing) =================
__global__ __launch_bounds__(256) void out_kernel(
    const float* __restrict__ og, const float* __restrict__ o_w, float* __restrict__ out)
{
    const int b = blockIdx.x;
    const int by = b / 6, bx = b % 6;

    __shared__ float As[32][68];
    __shared__ float Ws[32][68];

    const int tid = threadIdx.x;
    const int tx = tid & 15, ty = tid >> 4;
    const int r8 = tid >> 3;
    const int c4 = tid & 7;

    float acc[4][4] = {};
    for (int kc = 0; kc < DS; kc += 32) {
        __syncthreads();
#pragma unroll
        for (int pass = 0; pass < 2; ++pass) {
            int r = r8 + pass * 32;
            float4 sv = *(const float4*)(og + (by * 64 + r) * DS + kc + c4 * 4);
            float4 wvv = *(const float4*)(o_w + (bx * 64 + r) * DS + kc + c4 * 4);
            As[c4 * 4 + 0][r] = sv.x; As[c4 * 4 + 1][r] = sv.y;
            As[c4 * 4 + 2][r] = sv.z; As[c4 * 4 + 3][r] = sv.w;
            Ws[c4 * 4 + 0][r] = wvv.x; Ws[c4 * 4 + 1][r] = wvv.y;
            Ws[c4 * 4 + 2][r] = wvv.z; Ws[c4 * 4 + 3][r] = wvv.w;
        }
        __syncthreads();
#pragma unroll
        for (int k = 0; k < 32; ++k) {
            float4 a4 = *(const float4*)&As[k][ty * 4];
            float4 b4 = *(const float4*)&Ws[k][tx * 4];
            acc[0][0] += a4.x * b4.x; acc[0][1] += a4.x * b4.y; acc[0][2] += a4.x * b4.z; acc[0][3] += a4.x * b4.w;
            acc[1][0] += a4.y * b4.x; acc[1][1] += a4.y * b4.y; acc[1][2] += a4.y * b4.z; acc[1][3] += a4.y * b4.w;
            acc[2][0] += a4.z * b4.x; acc[2][1] += a4.z * b4.y; acc[2][2] += a4.z * b4.z; acc[2][3] += a4.z * b4.w;
            acc[3][0] += a4.w * b4.x; acc[3][1] += a4.w * b4.y; acc[3][2] += a4.w * b4.z; acc[3][3] += a4.w * b4.w;
        }
    }

    const int r0 = by * 64 + ty * 4;
    const int c0 = bx * 64 + tx * 4;
#pragma unroll
    for (int ii = 0; ii < 4; ++ii) {
        float4 v;
        v.x = acc[ii][0]; v.y = acc[ii][1]; v.z = acc[ii][2]; v.w = acc[ii][3];
        *(float4*)(out + (r0 + ii) * DS + c0) = v;
    }
}

extern "C" void kernel_launch(void* const* d_in, const int* in_sizes, int n_in,
                              void* d_out, int out_size, void* d_ws, size_t ws_size,
                              hipStream_t stream)
{
    const float* s      = (const float*)d_in[0];
    const float* z      = (const float*)d_in[1];
    const float* mask   = (const float*)d_in[2];
    const float* q_w    = (const float*)d_in[3];
    const float* q_b    = (const float*)d_in[4];
    const float* k_w    = (const float*)d_in[5];
    const float* v_w    = (const float*)d_in[6];
    const float* g_w    = (const float*)d_in[7];
    const float* o_w    = (const float*)d_in[8];
    const float* z_ln_w = (const float*)d_in[9];
    const float* z_ln_b = (const float*)d_in[10];
    const float* z_w    = (const float*)d_in[11];

    float* Q  = (float*)d_ws;
    float* K  = Q + S * DS;
    float* V  = K + S * DS;                 // natural [S][H*D] layout
    float* G  = V + S * DS;
    float* og = G + S * DS;
    float* scores = og + S * DS;            // H*S*S floats = 16.8 MB

    hipLaunchKernelGGL(proj_kernel, dim3(192), dim3(256), 0, stream,
                       s, q_w, q_b, k_w, v_w, g_w, Q, K, V, G);
    hipLaunchKernelGGL(score_kernel, dim3(4096), dim3(256), 0, stream,
                       z, mask, z_ln_w, z_ln_b, z_w, Q, K, scores);
    hipLaunchKernelGGL(spv_kernel, dim3(S), dim3(256), 0, stream,
                       scores, V, G, og);
    hipLaunchKernelGGL(out_kernel, dim3(48), dim3(256), 0, stream,
                       og, o_w, (float*)d_out);
}